// Round 1
// baseline (631.022 us; speedup 1.0000x reference)
//
#include <hip/hip_runtime.h>
#include <hip/hip_bf16.h>

typedef __bf16 bf16x8 __attribute__((ext_vector_type(8)));
typedef __bf16 bf16x4 __attribute__((ext_vector_type(4)));
typedef float  f32x4  __attribute__((ext_vector_type(4)));

#define MFMA(a,b,c) __builtin_amdgcn_mfma_f32_16x16x32_bf16((a),(b),(c),0,0,0)

// problem constants
#define NN_  42
#define E_   41
#define FB_  4096
#define SCALE_ 0.17677669529663687f  // 1/sqrt(32)

// ws layout, element offsets into __bf16* ws (layouts preserved == MFMA B-operand layout)
#define WB_WIN  0         // [128][32]
#define WB_QKV  4096      // [L][384][128]
#define WB_AO   102400    // [L][128][128]
#define WB_FF1  135168    // [L][256][128]
#define WB_FF2  200704    // [L][128][256]
#define WB_WOUT 266240    // [128][5376]
#define WB_X    954368    // [4096][5376] staged x_final (bf16)
#define PREP_N  954368

// smem layout (bytes), total 40704 -> 3 blocks/CU (was 57856 -> 2 blocks/CU).
//  [0,27648)      per-wave qk[48][72] (q cols 0..31, k cols 32..63), w*6912
//                 aliases (lifetime-disjoint):
//                   fbf [48][40]           @0      (init/embed only)
//                   bits int[48][4]        @3840   (init/embed only; pos as bitmask)
//                   adj int[123]           @4608   (init only)
//                   depth int[48]          @5104   (init only)
//                   hbf [48][264]          @0      (FF only; 25344 B)
//                   part float[384]        @25344  (ln_update only; wave3 qk rows 32+ are
//                   statsA/B float[48]     @26880/27072   dead post-scores barrier)
//  [27648,40704)  xbf/obf [48][136] bf16 (aliased; barrier guards swap)
#define SM_SZ 40704

// ---------------- weight cast to bf16 ----------------
__global__ void prep_bf16(const float* __restrict__ W_in, const float* __restrict__ qkv_w,
                          const float* __restrict__ ao_w, const float* __restrict__ ff1_w,
                          const float* __restrict__ ff2_w, const float* __restrict__ W_out,
                          __bf16* __restrict__ wb) {
  int i = blockIdx.x * 256 + threadIdx.x;
  float v;
  if      (i < 4096)   v = W_in[i];
  else if (i < 102400) v = qkv_w[i - 4096];
  else if (i < 135168) v = ao_w[i - 102400];
  else if (i < 200704) v = ff1_w[i - 135168];
  else if (i < 266240) v = ff2_w[i - 200704];
  else if (i < 954368) v = W_out[i - 266240];
  else return;
  wb[i] = (__bf16)v;
}

__device__ __forceinline__ bf16x8 ld8(const __bf16* p) { return *(const bf16x8*)p; }

__device__ __forceinline__ int pack2(float a, float b) {
  union { __bf16 h[2]; int i; } u;
  u.h[0] = (__bf16)a; u.h[1] = (__bf16)b;
  return u.i;
}

// C = A[48xK] * B^T for NB column-tiles; A in LDS (lda halfwords), B rows contiguous-k (global).
template <int NB, int KS>
__device__ __forceinline__ void gemm3xN(const __bf16* A, int lda, const __bf16* const (&B)[NB],
                                        int c16, int quad, f32x4 (&acc)[NB][3]) {
#pragma unroll
  for (int i = 0; i < NB; ++i) {
    acc[i][0] = f32x4{0,0,0,0}; acc[i][1] = f32x4{0,0,0,0}; acc[i][2] = f32x4{0,0,0,0};
  }
#pragma unroll
  for (int ks = 0; ks < KS; ++ks) {
    int ko = ks * 32 + quad * 8;
    bf16x8 a0 = ld8(A + c16 * lda + ko);
    bf16x8 a1 = ld8(A + (16 + c16) * lda + ko);
    bf16x8 a2 = ld8(A + (32 + c16) * lda + ko);
#pragma unroll
    for (int i = 0; i < NB; ++i) {
      bf16x8 b = ld8(B[i] + ko);
      acc[i][0] = MFMA(a0, b, acc[i][0]);
      acc[i][1] = MFMA(a1, b, acc[i][1]);
      acc[i][2] = MFMA(a2, b, acc[i][2]);
    }
  }
}

// LayerNorm update; res in C-layout (cols (2w+nt)*16+c16); rewrites res + xbf. 3 barriers.
__device__ __forceinline__ void ln_update(float (&res)[3][2][4], const float* __restrict__ g,
                                          const float* __restrict__ bb, __bf16* xbf, float* part,
                                          float* statsA, float* statsB, int tid, int w, int c16,
                                          int quad) {
#pragma unroll
  for (int mt = 0; mt < 3; ++mt)
#pragma unroll
    for (int r = 0; r < 4; ++r) {
      float s = res[mt][0][r] + res[mt][1][r];
      float ss = res[mt][0][r] * res[mt][0][r] + res[mt][1][r] * res[mt][1][r];
      s += __shfl_xor(s, 1); ss += __shfl_xor(ss, 1);
      s += __shfl_xor(s, 2); ss += __shfl_xor(ss, 2);
      s += __shfl_xor(s, 4); ss += __shfl_xor(ss, 4);
      s += __shfl_xor(s, 8); ss += __shfl_xor(ss, 8);
      if (c16 == 0) {
        int row = mt * 16 + quad * 4 + r;
        part[(w * 48 + row) * 2] = s; part[(w * 48 + row) * 2 + 1] = ss;
      }
    }
  __syncthreads();
  if (tid < 48) {
    float S = 0.f, SS = 0.f;
#pragma unroll
    for (int w2 = 0; w2 < 4; ++w2) { S += part[(w2 * 48 + tid) * 2]; SS += part[(w2 * 48 + tid) * 2 + 1]; }
    float mu = S * 0.0078125f;
    float var = fmaxf(SS * 0.0078125f - mu * mu, 0.f);
    statsA[tid] = mu; statsB[tid] = rsqrtf(var + 1e-5f);
  }
  __syncthreads();
  float gg[2], bv[2];
#pragma unroll
  for (int nt = 0; nt < 2; ++nt) { int col = (2 * w + nt) * 16 + c16; gg[nt] = g[col]; bv[nt] = bb[col]; }
#pragma unroll
  for (int mt = 0; mt < 3; ++mt)
#pragma unroll
    for (int r = 0; r < 4; ++r) {
      int row = mt * 16 + quad * 4 + r;
      float mu = statsA[row], rs = statsB[row];
#pragma unroll
      for (int nt = 0; nt < 2; ++nt) {
        float v = (res[mt][nt][r] - mu) * rs * gg[nt] + bv[nt];
        res[mt][nt][r] = v;
        xbf[row * 136 + (2 * w + nt) * 16 + c16] = (__bf16)(row < NN_ ? v : 0.f);
      }
    }
  __syncthreads();
}

// ---------------- per-tree fused encoder: wave-private attention ----------------
__global__ __launch_bounds__(256, 3) void tree_enc(
    const float* __restrict__ forest, const int* __restrict__ adjacency,
    const int* __restrict__ node_order, const float* __restrict__ b_in,
    const float* __restrict__ qkv_b, const float* __restrict__ ao_b,
    const float* __restrict__ ff1_b, const float* __restrict__ ff2_b,
    const float* __restrict__ ln1_g, const float* __restrict__ ln1_b,
    const float* __restrict__ ln2_g, const float* __restrict__ ln2_b,
    const __bf16* __restrict__ wb, __bf16* __restrict__ Xg) {
  const int f = blockIdx.x, tid = threadIdx.x;
  const int lane = tid & 63, w = tid >> 6, c16 = lane & 15, quad = lane >> 4;

  __shared__ alignas(16) unsigned char smem[SM_SZ];
  __bf16* qk     = (__bf16*)(smem + w * 6912);  // per-wave [48][72]: q cols 0..31, k cols 32..63
  __bf16* fbf    = (__bf16*)smem;               // [48][40] (init only)
  __bf16* hbf    = (__bf16*)smem;               // [48][264] (FF only)
  int*    bits_s = (int*)(smem + 3840);         // [48][4] pos bitmask (init/embed only)
  int*    adj_s  = (int*)(smem + 4608);
  int*    depth_s= (int*)(smem + 5104);
  float*  part   = (float*)(smem + 25344);      // ln_update only (qk tail dead then)
  float*  statsA = (float*)(smem + 26880);
  float*  statsB = (float*)(smem + 27072);
  __bf16* xbf    = (__bf16*)(smem + 27648);     // [48][136] x / attn-o (aliased)

  // ---- init phase 1: zeros (fbf + bits), adjacency, depths ----
  for (int i = tid; i < 1152; i += 256) ((int*)smem)[i] = 0;  // fbf [0,3840) + bits [3840,4608)
  if (tid < E_ * 3) adj_s[tid] = adjacency[f * (E_ * 3) + tid];
  if (w == 1) {
    int v = (lane < NN_) ? node_order[f * NN_ + lane] : 0;
    int mx = v;
#pragma unroll
    for (int m = 1; m < 64; m <<= 1) mx = max(mx, __shfl_xor(mx, m));
    if (lane < 48) depth_s[lane] = (lane < NN_) ? (mx - v) : 0;
  }
  __syncthreads();

  // ---- init phase 2: stage forest bf16 + positional walk (bitmask, by depth level) ----
  for (int i = tid; i < NN_ * 32; i += 256) {
    int r = i >> 5, c = i & 31;
    fbf[r * 40 + c] = (__bf16)forest[f * (NN_ * 32) + i];
  }
  if (w == 0) {
    // one edge per lane; process levels in parallel. pos values are 0/1 at distinct
    // indices (distinct ancestor depths) => 128-bit OR mask per node == the sum.
    int pl = -1, cl = 0, pd = 0, idx = 0;
    if (lane < E_) {
      int p = adj_s[lane * 3], c = adj_s[lane * 3 + 1], s = adj_s[lane * 3 + 2];
      if (p >= 0 && c >= 0) {
        pl = p - f * NN_; cl = c - f * NN_;
        int si = s + 1; si = si < 0 ? 0 : (si > 2 ? 2 : si);
        pd = depth_s[pl]; idx = pd * 3 + si;
      }
    }
    int dv = (lane < NN_) ? depth_s[lane] : 0;
#pragma unroll
    for (int m = 1; m < 64; m <<= 1) dv = max(dv, __shfl_xor(dv, m));
    int plc = pl < 0 ? 0 : pl;
    int bm = 1 << (idx & 31), wi = idx >> 5;
    int m0 = (wi == 0) ? bm : 0, m1 = (wi == 1) ? bm : 0;
    int m2 = (wi == 2) ? bm : 0, m3 = (wi == 3) ? bm : 0;
    for (int d = 0; d < dv; ++d) {
      int4 pb = *(int4*)&bits_s[plc * 4];
      if (pl >= 0 && pd == d) {
        int4 nb;
        nb.x = pb.x | m0; nb.y = pb.y | m1; nb.z = pb.z | m2; nb.w = pb.w | m3;
        *(int4*)&bits_s[cl * 4] = nb;
      }
      asm volatile("s_waitcnt lgkmcnt(0)" ::: "memory");
    }
  }
  __syncthreads();

  // ---- embed: x0 = forest @ W_in^T + b_in + pos ----
  float res[3][2][4];
  {
    const __bf16* Bw[2] = { wb + WB_WIN + ((2 * w) * 16 + c16) * 32,
                            wb + WB_WIN + ((2 * w + 1) * 16 + c16) * 32 };
    f32x4 ea[2][3];
    gemm3xN<2, 1>(fbf, 40, Bw, c16, quad, ea);
#pragma unroll
    for (int nt = 0; nt < 2; ++nt) {
      int col = (2 * w + nt) * 16 + c16;
      float bi = b_in[col];
      int wsel = col >> 5, shv = col & 31;
#pragma unroll
      for (int mt = 0; mt < 3; ++mt)
#pragma unroll
        for (int r = 0; r < 4; ++r) {
          int row = mt * 16 + quad * 4 + r;
          float v = ea[nt][mt][r] + bi + (float)((bits_s[row * 4 + wsel] >> shv) & 1);
          res[mt][nt][r] = v;
          xbf[row * 136 + col] = (__bf16)(row < NN_ ? v : 0.f);
        }
    }
  }
  __syncthreads();

  // ---- encoder layers ----
  for (int l = 0; l < 2; ++l) {
    // === per-wave qkv GEMM, head h = w; V kept in registers (packed bf16 pairs) ===
    int vp[2][3][2];  // [s = d-half][node m-tile][node pair]: V[mt*16+quad*4+2h..+1][s*16+c16]
    {
      const __bf16* qkvW = wb + WB_QKV + l * 384 * 128;
      const float* qbl = qkv_b + l * 384;
      f32x4 qa[6][3];
#pragma unroll
      for (int t = 0; t < 6; ++t) { qa[t][0] = f32x4{0,0,0,0}; qa[t][1] = f32x4{0,0,0,0}; qa[t][2] = f32x4{0,0,0,0}; }
      const __bf16* Bp[6];
#pragma unroll
      for (int t = 0; t < 6; ++t) {
        int p = t >> 1, s = t & 1;
        Bp[t] = qkvW + (p * 128 + w * 32 + s * 16 + c16) * 128;
      }
#pragma unroll
      for (int ks = 0; ks < 4; ++ks) {
        int ko = ks * 32 + quad * 8;
        bf16x8 a0 = ld8(xbf + c16 * 136 + ko);
        bf16x8 a1 = ld8(xbf + (16 + c16) * 136 + ko);
        bf16x8 a2 = ld8(xbf + (32 + c16) * 136 + ko);
#pragma unroll
        for (int t = 0; t < 6; ++t) {
          bf16x8 b = ld8(Bp[t] + ko);
          qa[t][0] = MFMA(a0, b, qa[t][0]);
          qa[t][1] = MFMA(a1, b, qa[t][1]);
          qa[t][2] = MFMA(a2, b, qa[t][2]);
        }
      }
#pragma unroll
      for (int t = 0; t < 6; ++t) {
        int p = t >> 1, s = t & 1;
        float bias = qbl[p * 128 + w * 32 + s * 16 + c16];
#pragma unroll
        for (int mt = 0; mt < 3; ++mt) {
          if (p == 2) {  // V -> registers (bf16 pair-packed), no LDS round-trip
            vp[s][mt][0] = pack2(qa[t][mt][0] + bias, qa[t][mt][1] + bias);
            vp[s][mt][1] = pack2(qa[t][mt][2] + bias, qa[t][mt][3] + bias);
          } else {       // Q (scaled) / K -> qk[node][col]
            int colo = (p == 0 ? 0 : 32) + s * 16 + c16;
#pragma unroll
            for (int r = 0; r < 4; ++r) {
              float v = qa[t][mt][r] + bias;
              if (p == 0) v *= SCALE_;
              qk[(mt * 16 + quad * 4 + r) * 72 + colo] = (__bf16)v;
            }
          }
        }
      }
    }
    __syncthreads();  // guards xbf reads (qkv) vs obf writes (PV) across waves

    // === scores S^T = K Q^T, 9 tiles in-register ===
    f32x4 st[3][3];
    {
      bf16x8 ka[3], qb2[3];
#pragma unroll
      for (int m = 0; m < 3; ++m) ka[m] = ld8(qk + (m * 16 + c16) * 72 + 32 + quad * 8);
#pragma unroll
      for (int n = 0; n < 3; ++n) qb2[n] = ld8(qk + (n * 16 + c16) * 72 + quad * 8);
#pragma unroll
      for (int m = 0; m < 3; ++m)
#pragma unroll
        for (int n = 0; n < 3; ++n) {
          f32x4 z{0,0,0,0};
          st[m][n] = MFMA(ka[m], qb2[n], z);
        }
    }

    // === softmax fully in-register (query = n-tile*16 + c16; keys on quad/reg) ===
    int dwp[3][3][2];  // packed P bf16 pairs [key-tile][query-tile][dword]
#pragma unroll
    for (int n = 0; n < 3; ++n) {
      float mx = -3.0e38f;
#pragma unroll
      for (int m = 0; m < 3; ++m)
#pragma unroll
        for (int r = 0; r < 4; ++r) {
          bool valid = (m < 2) || (quad * 4 + r < 10);  // key < 42
          mx = fmaxf(mx, valid ? st[m][n][r] : -3.0e38f);
        }
      mx = fmaxf(mx, __shfl_xor(mx, 16));
      mx = fmaxf(mx, __shfl_xor(mx, 32));
      float sm = 0.f, ev[3][4];
#pragma unroll
      for (int m = 0; m < 3; ++m)
#pragma unroll
        for (int r = 0; r < 4; ++r) {
          bool valid = (m < 2) || (quad * 4 + r < 10);
          float e = valid ? __expf(st[m][n][r] - mx) : 0.f;
          ev[m][r] = e; sm += e;
        }
      sm += __shfl_xor(sm, 16);
      sm += __shfl_xor(sm, 32);
      float inv = 1.f / sm;
#pragma unroll
      for (int m = 0; m < 3; ++m) {
        dwp[m][n][0] = pack2(ev[m][0] * inv, ev[m][1] * inv);
        dwp[m][n][1] = pack2(ev[m][2] * inv, ev[m][3] * inv);
      }
    }

    // === PV: both P and V^T fragments via shuffle-transpose (no LDS round-trip) ===
    f32x4 ov[3][2];
#pragma unroll
    for (int mtq = 0; mtq < 3; ++mtq) { ov[mtq][0] = f32x4{0,0,0,0}; ov[mtq][1] = f32x4{0,0,0,0}; }
    int sl0 = (2 * (quad & 1)) * 16 + c16, sl1 = sl0 + 16;
    bool hi = quad > 1;
#pragma unroll
    for (int ks = 0; ks < 2; ++ks) {
      // B-operand: V[g..g+7][d=nt*16+c16], g = koB(quad). dword m holds nodes (g+2m, g+2m+1):
      //   src lane = (((quad<<1)+(m>>1))&3)*16 + c16, reg = vp[nt][mt_src][m&1],
      //   mt_src = quad>>1 (ks=0) | 2 (ks=1).  Matches A-operand koB exactly (A=0 where clamped).
      bf16x8 bv[2];
#pragma unroll
      for (int nt = 0; nt < 2; ++nt) {
        union { int i[4]; bf16x8 v; } U;
#pragma unroll
        for (int m = 0; m < 4; ++m) {
          int srcl = (((quad << 1) + (m >> 1)) & 3) * 16 + c16;
          if (ks == 0) {
            int x0 = __shfl(vp[nt][0][m & 1], srcl);
            int x1 = __shfl(vp[nt][1][m & 1], srcl);
            U.i[m] = (quad >> 1) ? x1 : x0;
          } else {
            U.i[m] = __shfl(vp[nt][2][m & 1], srcl);
          }
        }
        bv[nt] = U.v;
      }
      int lo = 2 * ks;
#pragma unroll
      for (int mtq = 0; mtq < 3; ++mtq) {
        int a0 = __shfl(dwp[lo][mtq][0], sl0), a1 = __shfl(dwp[lo][mtq][1], sl0);
        int a2 = __shfl(dwp[lo][mtq][0], sl1), a3 = __shfl(dwp[lo][mtq][1], sl1);
        int b0 = 0, b1 = 0, b2 = 0, b3 = 0;
        if (ks == 0) {
          b0 = __shfl(dwp[1][mtq][0], sl0); b1 = __shfl(dwp[1][mtq][1], sl0);
          b2 = __shfl(dwp[1][mtq][0], sl1); b3 = __shfl(dwp[1][mtq][1], sl1);
        }
        union { int i[4]; bf16x8 v; } A;
        A.i[0] = hi ? b0 : a0; A.i[1] = hi ? b1 : a1;
        A.i[2] = hi ? b2 : a2; A.i[3] = hi ? b3 : a3;
        ov[mtq][0] = MFMA(A.v, bv[0], ov[mtq][0]);
        ov[mtq][1] = MFMA(A.v, bv[1], ov[mtq][1]);
      }
    }
    // obf (= xbf alias) write: head slab cols w*32..w*32+31
#pragma unroll
    for (int mtq = 0; mtq < 3; ++mtq)
#pragma unroll
      for (int nt = 0; nt < 2; ++nt)
#pragma unroll
        for (int r = 0; r < 4; ++r) {
          int row = mtq * 16 + quad * 4 + r;
          xbf[row * 136 + w * 32 + nt * 16 + c16] = (__bf16)(row < NN_ ? ov[mtq][nt][r] : 0.f);
        }
    __syncthreads();

    // === attn-out + residual ===
    {
      const __bf16* aoW = wb + WB_AO + l * 128 * 128;
      const __bf16* Bs[2] = { aoW + ((2 * w) * 16 + c16) * 128, aoW + ((2 * w + 1) * 16 + c16) * 128 };
      f32x4 aa[2][3];
      gemm3xN<2, 4>(xbf, 136, Bs, c16, quad, aa);
#pragma unroll
      for (int nt = 0; nt < 2; ++nt) {
        float ab = ao_b[l * 128 + (2 * w + nt) * 16 + c16];
#pragma unroll
        for (int mt = 0; mt < 3; ++mt)
#pragma unroll
          for (int r = 0; r < 4; ++r) res[mt][nt][r] += aa[nt][mt][r] + ab;
      }
    }
    ln_update(res, ln1_g + l * 128, ln1_b + l * 128, xbf, part, statsA, statsB, tid, w, c16, quad);

    // === FF1 -> hbf (relu, bf16) ===
    {
      const __bf16* f1W = wb + WB_FF1 + l * 256 * 128;
      const __bf16* Bs[4] = { f1W + ((4 * w) * 16 + c16) * 128, f1W + ((4 * w + 1) * 16 + c16) * 128,
                              f1W + ((4 * w + 2) * 16 + c16) * 128, f1W + ((4 * w + 3) * 16 + c16) * 128 };
      f32x4 fa[4][3];
      gemm3xN<4, 4>(xbf, 136, Bs, c16, quad, fa);
#pragma unroll
      for (int nt = 0; nt < 4; ++nt) {
        int col = (4 * w + nt) * 16 + c16;
        float b1 = ff1_b[l * 256 + col];
#pragma unroll
        for (int mt = 0; mt < 3; ++mt)
#pragma unroll
          for (int r = 0; r < 4; ++r) {
            int row = mt * 16 + quad * 4 + r;
            float v = fmaxf(fa[nt][mt][r] + b1, 0.f);
            hbf[row * 264 + col] = (__bf16)(row < NN_ ? v : 0.f);
          }
      }
    }
    __syncthreads();

    // === FF2 + residual ===
    {
      const __bf16* f2W = wb + WB_FF2 + l * 128 * 256;
      const __bf16* Bs[2] = { f2W + ((2 * w) * 16 + c16) * 256, f2W + ((2 * w + 1) * 16 + c16) * 256 };
      f32x4 fa[2][3];
      gemm3xN<2, 8>(hbf, 264, Bs, c16, quad, fa);
#pragma unroll
      for (int nt = 0; nt < 2; ++nt) {
        float fb2 = ff2_b[l * 128 + (2 * w + nt) * 16 + c16];
#pragma unroll
        for (int mt = 0; mt < 3; ++mt)
#pragma unroll
          for (int r = 0; r < 4; ++r) res[mt][nt][r] += fa[nt][mt][r] + fb2;
      }
    }
    ln_update(res, ln2_g + l * 128, ln2_b + l * 128, xbf, part, statsA, statsB, tid, w, c16, quad);
  }

  // ---- stage out: x_final (bf16) -> ws X[f][5376] ----
  {
    __bf16* Xf = Xg + (size_t)f * 5376;
    for (int c = tid; c < 672; c += 256) {
      int row = c >> 4, co = (c & 15) * 8;
      *(bf16x8*)(Xf + row * 128 + co) = ld8(xbf + row * 136 + co);
    }
  }
}

// ---------------- output projection + final LN, K split 4-way across waves ----------------
__global__ __launch_bounds__(1024) void wout_k(const __bf16* __restrict__ X,
                                               const __bf16* __restrict__ Wb,
                                               const float* __restrict__ b_out,
                                               const float* __restrict__ lnf_g,
                                               const float* __restrict__ lnf_b,
                                               float* __restrict__ out) {
  const int blk = blockIdx.x, tid = threadIdx.x;
  const int lane = tid & 63, w2 = tid >> 6, wc = w2 & 3, kh = w2 >> 2;  // wc 0..3, kh 0..3
  const int c16 = lane & 15, quad = lane >> 4;
  __shared__ float cout[64 * 132];
  f32x4 acc0{0,0,0,0}, acc1{0,0,0,0};
  const __bf16* Ar = X + (size_t)(blk * 16 + c16) * 5376 + kh * 1344;
  const __bf16* B0 = Wb + (size_t)((2 * wc) * 16 + c16) * 5376 + kh * 1344;
  const __bf16* B1 = Wb + (size_t)((2 * wc + 1) * 16 + c16) * 5376 + kh * 1344;
#pragma unroll 3
  for (int ks = 0; ks < 42; ++ks) {
    int ko = ks * 32 + quad * 8;
    bf16x8 a = ld8(Ar + ko);
    acc0 = MFMA(a, ld8(B0 + ko), acc0);
    acc1 = MFMA(a, ld8(B1 + ko), acc1);
  }
#pragma unroll
  for (int nt = 0; nt < 2; ++nt) {
    f32x4 a = nt ? acc1 : acc0;
#pragma unroll
    for (int r = 0; r < 4; ++r) cout[(kh * 16 + quad * 4 + r) * 132 + (2 * wc + nt) * 16 + c16] = a[r];
  }
  __syncthreads();
  if (w2 < 4) {
#pragma unroll
    for (int rr = 0; rr < 4; ++rr) {
      int row = w2 * 4 + rr;
      float v0 = cout[row * 132 + lane] + cout[(16 + row) * 132 + lane] +
                 cout[(32 + row) * 132 + lane] + cout[(48 + row) * 132 + lane] + b_out[lane];
      float v1 = cout[row * 132 + 64 + lane] + cout[(16 + row) * 132 + 64 + lane] +
                 cout[(32 + row) * 132 + 64 + lane] + cout[(48 + row) * 132 + 64 + lane] + b_out[64 + lane];
      float s = v0 + v1, ss = v0 * v0 + v1 * v1;
#pragma unroll
      for (int m = 1; m < 64; m <<= 1) { s += __shfl_xor(s, m); ss += __shfl_xor(ss, m); }
      float mu = s * 0.0078125f;
      float var = fmaxf(ss * 0.0078125f - mu * mu, 0.f);
      float rs = rsqrtf(var + 1e-5f);
      size_t o = (size_t)(blk * 16 + row) * 128;
      out[o + lane] = (v0 - mu) * rs * lnf_g[lane] + lnf_b[lane];
      out[o + 64 + lane] = (v1 - mu) * rs * lnf_g[64 + lane] + lnf_b[64 + lane];
    }
  }
}

extern "C" void kernel_launch(void* const* d_in, const int* in_sizes, int n_in,
                              void* d_out, int out_size, void* d_ws, size_t ws_size,
                              hipStream_t stream) {
  const float* forest     = (const float*)d_in[0];
  const int*   adjacency  = (const int*)d_in[1];
  const int*   node_order = (const int*)d_in[2];
  const float* W_in       = (const float*)d_in[3];
  const float* b_in       = (const float*)d_in[4];
  const float* qkv_w      = (const float*)d_in[5];
  const float* qkv_b      = (const float*)d_in[6];
  const float* ao_w       = (const float*)d_in[7];
  const float* ao_b       = (const float*)d_in[8];
  const float* ff1_w      = (const float*)d_in[9];
  const float* ff1_b      = (const float*)d_in[10];
  const float* ff2_w      = (const float*)d_in[11];
  const float* ff2_b      = (const float*)d_in[12];
  const float* ln1_g      = (const float*)d_in[13];
  const float* ln1_b      = (const float*)d_in[14];
  const float* ln2_g      = (const float*)d_in[15];
  const float* ln2_b      = (const float*)d_in[16];
  const float* b_out      = (const float*)d_in[18];
  const float* lnf_g      = (const float*)d_in[19];
  const float* lnf_b      = (const float*)d_in[20];
  __bf16* wb = (__bf16*)d_ws;
  float* out = (float*)d_out;

  prep_bf16<<<dim3(PREP_N / 256), dim3(256), 0, stream>>>(W_in, qkv_w, ao_w, ff1_w, ff2_w,
                                                          (const float*)d_in[17], wb);
  tree_enc<<<dim3(FB_), dim3(256), 0, stream>>>(forest, adjacency, node_order, b_in, qkv_b, ao_b,
                                                ff1_b, ff2_b, ln1_g, ln1_b, ln2_g, ln2_b, wb,
                                                wb + WB_X);
  wout_k<<<dim3(FB_ / 16), dim3(1024), 0, stream>>>(wb + WB_X, wb + WB_WOUT, b_out, lnf_g, lnf_b,
                                                    out);
}

// Round 2
// 546.087 us; speedup vs baseline: 1.1555x; 1.1555x over previous
//
#include <hip/hip_runtime.h>
#include <hip/hip_bf16.h>

typedef __bf16 bf16x8 __attribute__((ext_vector_type(8)));
typedef __bf16 bf16x4 __attribute__((ext_vector_type(4)));
typedef float  f32x4  __attribute__((ext_vector_type(4)));

#define MFMA(a,b,c) __builtin_amdgcn_mfma_f32_16x16x32_bf16((a),(b),(c),0,0,0)

// problem constants
#define NN_  42
#define E_   41
#define FB_  4096
#define SCALE_ 0.17677669529663687f  // 1/sqrt(32)

// ws layout, element offsets into __bf16* ws (layouts preserved == MFMA B-operand layout)
#define WB_WIN  0         // [128][32]
#define WB_QKV  4096      // [L][384][128]
#define WB_AO   102400    // [L][128][128]
#define WB_FF1  135168    // [L][256][128]
#define WB_FF2  200704    // [L][128][256]
#define WB_WOUT 266240    // [128][5376]
#define WB_X    954368    // [4096][5376] staged x_final (bf16)
#define PREP_N  954368

// smem layout (bytes), total 40704 -> 3 blocks/CU (LDS-limited).
//  [0,27648)      per-wave qk[48][72] (q cols 0..31, k cols 32..63), w*6912
//                 aliases (lifetime-disjoint):
//                   fbf [48][40]           @0      (init/embed only)
//                   bits int[48][4]        @3840   (init/embed only; pos as bitmask)
//                   adj int[123]           @4608   (init only)
//                   depth int[48]          @5104   (init only)
//                   hbf [48][264]          @0      (FF only; 25344 B)
//                   part float[384]        @25344  (ln_update only; wave3 qk rows 32+ are
//                   statsA/B float[48]     @26880/27072   dead post-scores barrier)
//  [27648,40704)  xbf/obf [48][136] bf16 (aliased; barrier guards swap)
// NOTE: __launch_bounds__(256,3) made the backend cap unified VGPR+AGPR at ~84 arch regs
// and spill ~700 MB/launch to scratch (round-1 counters). (256,2) -> 124-155 regs, no
// spill; floor(512/VGPR)>=3 waves/EU so LDS stays the occupancy limiter at 3 blocks/CU.
#define SM_SZ 40704

// ---------------- weight cast to bf16 ----------------
__global__ void prep_bf16(const float* __restrict__ W_in, const float* __restrict__ qkv_w,
                          const float* __restrict__ ao_w, const float* __restrict__ ff1_w,
                          const float* __restrict__ ff2_w, const float* __restrict__ W_out,
                          __bf16* __restrict__ wb) {
  int i = blockIdx.x * 256 + threadIdx.x;
  float v;
  if      (i < 4096)   v = W_in[i];
  else if (i < 102400) v = qkv_w[i - 4096];
  else if (i < 135168) v = ao_w[i - 102400];
  else if (i < 200704) v = ff1_w[i - 135168];
  else if (i < 266240) v = ff2_w[i - 200704];
  else if (i < 954368) v = W_out[i - 266240];
  else return;
  wb[i] = (__bf16)v;
}

__device__ __forceinline__ bf16x8 ld8(const __bf16* p) { return *(const bf16x8*)p; }

__device__ __forceinline__ int pack2(float a, float b) {
  union { __bf16 h[2]; int i; } u;
  u.h[0] = (__bf16)a; u.h[1] = (__bf16)b;
  return u.i;
}

// C = A[48xK] * B^T for NB column-tiles; A in LDS (lda halfwords), B rows contiguous-k (global).
template <int NB, int KS>
__device__ __forceinline__ void gemm3xN(const __bf16* A, int lda, const __bf16* const (&B)[NB],
                                        int c16, int quad, f32x4 (&acc)[NB][3]) {
#pragma unroll
  for (int i = 0; i < NB; ++i) {
    acc[i][0] = f32x4{0,0,0,0}; acc[i][1] = f32x4{0,0,0,0}; acc[i][2] = f32x4{0,0,0,0};
  }
#pragma unroll
  for (int ks = 0; ks < KS; ++ks) {
    int ko = ks * 32 + quad * 8;
    bf16x8 a0 = ld8(A + c16 * lda + ko);
    bf16x8 a1 = ld8(A + (16 + c16) * lda + ko);
    bf16x8 a2 = ld8(A + (32 + c16) * lda + ko);
#pragma unroll
    for (int i = 0; i < NB; ++i) {
      bf16x8 b = ld8(B[i] + ko);
      acc[i][0] = MFMA(a0, b, acc[i][0]);
      acc[i][1] = MFMA(a1, b, acc[i][1]);
      acc[i][2] = MFMA(a2, b, acc[i][2]);
    }
  }
}

// LayerNorm update; res in C-layout (cols (2w+nt)*16+c16); rewrites res + xbf. 3 barriers.
__device__ __forceinline__ void ln_update(float (&res)[3][2][4], const float* __restrict__ g,
                                          const float* __restrict__ bb, __bf16* xbf, float* part,
                                          float* statsA, float* statsB, int tid, int w, int c16,
                                          int quad) {
#pragma unroll
  for (int mt = 0; mt < 3; ++mt)
#pragma unroll
    for (int r = 0; r < 4; ++r) {
      float s = res[mt][0][r] + res[mt][1][r];
      float ss = res[mt][0][r] * res[mt][0][r] + res[mt][1][r] * res[mt][1][r];
      s += __shfl_xor(s, 1); ss += __shfl_xor(ss, 1);
      s += __shfl_xor(s, 2); ss += __shfl_xor(ss, 2);
      s += __shfl_xor(s, 4); ss += __shfl_xor(ss, 4);
      s += __shfl_xor(s, 8); ss += __shfl_xor(ss, 8);
      if (c16 == 0) {
        int row = mt * 16 + quad * 4 + r;
        part[(w * 48 + row) * 2] = s; part[(w * 48 + row) * 2 + 1] = ss;
      }
    }
  __syncthreads();
  if (tid < 48) {
    float S = 0.f, SS = 0.f;
#pragma unroll
    for (int w2 = 0; w2 < 4; ++w2) { S += part[(w2 * 48 + tid) * 2]; SS += part[(w2 * 48 + tid) * 2 + 1]; }
    float mu = S * 0.0078125f;
    float var = fmaxf(SS * 0.0078125f - mu * mu, 0.f);
    statsA[tid] = mu; statsB[tid] = rsqrtf(var + 1e-5f);
  }
  __syncthreads();
  float gg[2], bv[2];
#pragma unroll
  for (int nt = 0; nt < 2; ++nt) { int col = (2 * w + nt) * 16 + c16; gg[nt] = g[col]; bv[nt] = bb[col]; }
#pragma unroll
  for (int mt = 0; mt < 3; ++mt)
#pragma unroll
    for (int r = 0; r < 4; ++r) {
      int row = mt * 16 + quad * 4 + r;
      float mu = statsA[row], rs = statsB[row];
#pragma unroll
      for (int nt = 0; nt < 2; ++nt) {
        float v = (res[mt][nt][r] - mu) * rs * gg[nt] + bv[nt];
        res[mt][nt][r] = v;
        xbf[row * 136 + (2 * w + nt) * 16 + c16] = (__bf16)(row < NN_ ? v : 0.f);
      }
    }
  __syncthreads();
}

// ---------------- per-tree fused encoder: wave-private attention ----------------
__global__ __launch_bounds__(256, 2) void tree_enc(
    const float* __restrict__ forest, const int* __restrict__ adjacency,
    const int* __restrict__ node_order, const float* __restrict__ b_in,
    const float* __restrict__ qkv_b, const float* __restrict__ ao_b,
    const float* __restrict__ ff1_b, const float* __restrict__ ff2_b,
    const float* __restrict__ ln1_g, const float* __restrict__ ln1_b,
    const float* __restrict__ ln2_g, const float* __restrict__ ln2_b,
    const __bf16* __restrict__ wb, __bf16* __restrict__ Xg) {
  const int f = blockIdx.x, tid = threadIdx.x;
  const int lane = tid & 63, w = tid >> 6, c16 = lane & 15, quad = lane >> 4;

  __shared__ alignas(16) unsigned char smem[SM_SZ];
  __bf16* qk     = (__bf16*)(smem + w * 6912);  // per-wave [48][72]: q cols 0..31, k cols 32..63
  __bf16* fbf    = (__bf16*)smem;               // [48][40] (init only)
  __bf16* hbf    = (__bf16*)smem;               // [48][264] (FF only)
  int*    bits_s = (int*)(smem + 3840);         // [48][4] pos bitmask (init/embed only)
  int*    adj_s  = (int*)(smem + 4608);
  int*    depth_s= (int*)(smem + 5104);
  float*  part   = (float*)(smem + 25344);      // ln_update only (qk tail dead then)
  float*  statsA = (float*)(smem + 26880);
  float*  statsB = (float*)(smem + 27072);
  __bf16* xbf    = (__bf16*)(smem + 27648);     // [48][136] x / attn-o (aliased)

  // ---- init phase 1: zeros (fbf + bits), adjacency, depths ----
  for (int i = tid; i < 1152; i += 256) ((int*)smem)[i] = 0;  // fbf [0,3840) + bits [3840,4608)
  if (tid < E_ * 3) adj_s[tid] = adjacency[f * (E_ * 3) + tid];
  if (w == 1) {
    int v = (lane < NN_) ? node_order[f * NN_ + lane] : 0;
    int mx = v;
#pragma unroll
    for (int m = 1; m < 64; m <<= 1) mx = max(mx, __shfl_xor(mx, m));
    if (lane < 48) depth_s[lane] = (lane < NN_) ? (mx - v) : 0;
  }
  __syncthreads();

  // ---- init phase 2: stage forest bf16 + positional walk (bitmask, by depth level) ----
  for (int i = tid; i < NN_ * 32; i += 256) {
    int r = i >> 5, c = i & 31;
    fbf[r * 40 + c] = (__bf16)forest[f * (NN_ * 32) + i];
  }
  if (w == 0) {
    // one edge per lane; process levels in parallel. pos values are 0/1 at distinct
    // indices (distinct ancestor depths) => 128-bit OR mask per node == the sum.
    int pl = -1, cl = 0, pd = 0, idx = 0;
    if (lane < E_) {
      int p = adj_s[lane * 3], c = adj_s[lane * 3 + 1], s = adj_s[lane * 3 + 2];
      if (p >= 0 && c >= 0) {
        pl = p - f * NN_; cl = c - f * NN_;
        int si = s + 1; si = si < 0 ? 0 : (si > 2 ? 2 : si);
        pd = depth_s[pl]; idx = pd * 3 + si;
      }
    }
    int dv = (lane < NN_) ? depth_s[lane] : 0;
#pragma unroll
    for (int m = 1; m < 64; m <<= 1) dv = max(dv, __shfl_xor(dv, m));
    int plc = pl < 0 ? 0 : pl;
    int bm = 1 << (idx & 31), wi = idx >> 5;
    int m0 = (wi == 0) ? bm : 0, m1 = (wi == 1) ? bm : 0;
    int m2 = (wi == 2) ? bm : 0, m3 = (wi == 3) ? bm : 0;
    for (int d = 0; d < dv; ++d) {
      int4 pb = *(int4*)&bits_s[plc * 4];
      if (pl >= 0 && pd == d) {
        int4 nb;
        nb.x = pb.x | m0; nb.y = pb.y | m1; nb.z = pb.z | m2; nb.w = pb.w | m3;
        *(int4*)&bits_s[cl * 4] = nb;
      }
      asm volatile("s_waitcnt lgkmcnt(0)" ::: "memory");
    }
  }
  __syncthreads();

  // ---- embed: x0 = forest @ W_in^T + b_in + pos ----
  float res[3][2][4];
  {
    const __bf16* Bw[2] = { wb + WB_WIN + ((2 * w) * 16 + c16) * 32,
                            wb + WB_WIN + ((2 * w + 1) * 16 + c16) * 32 };
    f32x4 ea[2][3];
    gemm3xN<2, 1>(fbf, 40, Bw, c16, quad, ea);
#pragma unroll
    for (int nt = 0; nt < 2; ++nt) {
      int col = (2 * w + nt) * 16 + c16;
      float bi = b_in[col];
      int wsel = col >> 5, shv = col & 31;
#pragma unroll
      for (int mt = 0; mt < 3; ++mt)
#pragma unroll
        for (int r = 0; r < 4; ++r) {
          int row = mt * 16 + quad * 4 + r;
          float v = ea[nt][mt][r] + bi + (float)((bits_s[row * 4 + wsel] >> shv) & 1);
          res[mt][nt][r] = v;
          xbf[row * 136 + col] = (__bf16)(row < NN_ ? v : 0.f);
        }
    }
  }
  __syncthreads();

  // ---- encoder layers ----
  for (int l = 0; l < 2; ++l) {
    // === per-wave qkv GEMM, head h = w; V kept in registers (packed bf16 pairs) ===
    int vp[2][3][2];  // [s = d-half][node m-tile][node pair]: V[mt*16+quad*4+2h..+1][s*16+c16]
    {
      const __bf16* qkvW = wb + WB_QKV + l * 384 * 128;
      const float* qbl = qkv_b + l * 384;
      f32x4 qa[6][3];
#pragma unroll
      for (int t = 0; t < 6; ++t) { qa[t][0] = f32x4{0,0,0,0}; qa[t][1] = f32x4{0,0,0,0}; qa[t][2] = f32x4{0,0,0,0}; }
      const __bf16* Bp[6];
#pragma unroll
      for (int t = 0; t < 6; ++t) {
        int p = t >> 1, s = t & 1;
        Bp[t] = qkvW + (p * 128 + w * 32 + s * 16 + c16) * 128;
      }
#pragma unroll
      for (int ks = 0; ks < 4; ++ks) {
        int ko = ks * 32 + quad * 8;
        bf16x8 a0 = ld8(xbf + c16 * 136 + ko);
        bf16x8 a1 = ld8(xbf + (16 + c16) * 136 + ko);
        bf16x8 a2 = ld8(xbf + (32 + c16) * 136 + ko);
#pragma unroll
        for (int t = 0; t < 6; ++t) {
          bf16x8 b = ld8(Bp[t] + ko);
          qa[t][0] = MFMA(a0, b, qa[t][0]);
          qa[t][1] = MFMA(a1, b, qa[t][1]);
          qa[t][2] = MFMA(a2, b, qa[t][2]);
        }
      }
#pragma unroll
      for (int t = 0; t < 6; ++t) {
        int p = t >> 1, s = t & 1;
        float bias = qbl[p * 128 + w * 32 + s * 16 + c16];
#pragma unroll
        for (int mt = 0; mt < 3; ++mt) {
          if (p == 2) {  // V -> registers (bf16 pair-packed), no LDS round-trip
            vp[s][mt][0] = pack2(qa[t][mt][0] + bias, qa[t][mt][1] + bias);
            vp[s][mt][1] = pack2(qa[t][mt][2] + bias, qa[t][mt][3] + bias);
          } else {       // Q (scaled) / K -> qk[node][col]
            int colo = (p == 0 ? 0 : 32) + s * 16 + c16;
#pragma unroll
            for (int r = 0; r < 4; ++r) {
              float v = qa[t][mt][r] + bias;
              if (p == 0) v *= SCALE_;
              qk[(mt * 16 + quad * 4 + r) * 72 + colo] = (__bf16)v;
            }
          }
        }
      }
    }
    __syncthreads();  // guards xbf reads (qkv) vs obf writes (PV) across waves

    // === scores S^T = K Q^T, 9 tiles in-register ===
    f32x4 st[3][3];
    {
      bf16x8 ka[3], qb2[3];
#pragma unroll
      for (int m = 0; m < 3; ++m) ka[m] = ld8(qk + (m * 16 + c16) * 72 + 32 + quad * 8);
#pragma unroll
      for (int n = 0; n < 3; ++n) qb2[n] = ld8(qk + (n * 16 + c16) * 72 + quad * 8);
#pragma unroll
      for (int m = 0; m < 3; ++m)
#pragma unroll
        for (int n = 0; n < 3; ++n) {
          f32x4 z{0,0,0,0};
          st[m][n] = MFMA(ka[m], qb2[n], z);
        }
    }

    // === softmax fully in-register (query = n-tile*16 + c16; keys on quad/reg) ===
    int dwp[3][3][2];  // packed P bf16 pairs [key-tile][query-tile][dword]
#pragma unroll
    for (int n = 0; n < 3; ++n) {
      float mx = -3.0e38f;
#pragma unroll
      for (int m = 0; m < 3; ++m)
#pragma unroll
        for (int r = 0; r < 4; ++r) {
          bool valid = (m < 2) || (quad * 4 + r < 10);  // key < 42
          mx = fmaxf(mx, valid ? st[m][n][r] : -3.0e38f);
        }
      mx = fmaxf(mx, __shfl_xor(mx, 16));
      mx = fmaxf(mx, __shfl_xor(mx, 32));
      float sm = 0.f, ev[3][4];
#pragma unroll
      for (int m = 0; m < 3; ++m)
#pragma unroll
        for (int r = 0; r < 4; ++r) {
          bool valid = (m < 2) || (quad * 4 + r < 10);
          float e = valid ? __expf(st[m][n][r] - mx) : 0.f;
          ev[m][r] = e; sm += e;
        }
      sm += __shfl_xor(sm, 16);
      sm += __shfl_xor(sm, 32);
      float inv = 1.f / sm;
#pragma unroll
      for (int m = 0; m < 3; ++m) {
        dwp[m][n][0] = pack2(ev[m][0] * inv, ev[m][1] * inv);
        dwp[m][n][1] = pack2(ev[m][2] * inv, ev[m][3] * inv);
      }
    }

    // === PV: both P and V^T fragments via shuffle-transpose (no LDS round-trip) ===
    f32x4 ov[3][2];
#pragma unroll
    for (int mtq = 0; mtq < 3; ++mtq) { ov[mtq][0] = f32x4{0,0,0,0}; ov[mtq][1] = f32x4{0,0,0,0}; }
    int sl0 = (2 * (quad & 1)) * 16 + c16, sl1 = sl0 + 16;
    bool hi = quad > 1;
#pragma unroll
    for (int ks = 0; ks < 2; ++ks) {
      // B-operand: V[g..g+7][d=nt*16+c16], g = koB(quad). dword m holds nodes (g+2m, g+2m+1):
      //   src lane = (((quad<<1)+(m>>1))&3)*16 + c16, reg = vp[nt][mt_src][m&1],
      //   mt_src = quad>>1 (ks=0) | 2 (ks=1).  Matches A-operand koB exactly (A=0 there).
      bf16x8 bv[2];
#pragma unroll
      for (int nt = 0; nt < 2; ++nt) {
        union { int i[4]; bf16x8 v; } U;
#pragma unroll
        for (int m = 0; m < 4; ++m) {
          int srcl = (((quad << 1) + (m >> 1)) & 3) * 16 + c16;
          if (ks == 0) {
            int x0 = __shfl(vp[nt][0][m & 1], srcl);
            int x1 = __shfl(vp[nt][1][m & 1], srcl);
            U.i[m] = (quad >> 1) ? x1 : x0;
          } else {
            U.i[m] = __shfl(vp[nt][2][m & 1], srcl);
          }
        }
        bv[nt] = U.v;
      }
      int lo = 2 * ks;
#pragma unroll
      for (int mtq = 0; mtq < 3; ++mtq) {
        int a0 = __shfl(dwp[lo][mtq][0], sl0), a1 = __shfl(dwp[lo][mtq][1], sl0);
        int a2 = __shfl(dwp[lo][mtq][0], sl1), a3 = __shfl(dwp[lo][mtq][1], sl1);
        int b0 = 0, b1 = 0, b2 = 0, b3 = 0;
        if (ks == 0) {
          b0 = __shfl(dwp[1][mtq][0], sl0); b1 = __shfl(dwp[1][mtq][1], sl0);
          b2 = __shfl(dwp[1][mtq][0], sl1); b3 = __shfl(dwp[1][mtq][1], sl1);
        }
        union { int i[4]; bf16x8 v; } A;
        A.i[0] = hi ? b0 : a0; A.i[1] = hi ? b1 : a1;
        A.i[2] = hi ? b2 : a2; A.i[3] = hi ? b3 : a3;
        ov[mtq][0] = MFMA(A.v, bv[0], ov[mtq][0]);
        ov[mtq][1] = MFMA(A.v, bv[1], ov[mtq][1]);
      }
    }
    // obf (= xbf alias) write: head slab cols w*32..w*32+31
#pragma unroll
    for (int mtq = 0; mtq < 3; ++mtq)
#pragma unroll
      for (int nt = 0; nt < 2; ++nt)
#pragma unroll
        for (int r = 0; r < 4; ++r) {
          int row = mtq * 16 + quad * 4 + r;
          xbf[row * 136 + w * 32 + nt * 16 + c16] = (__bf16)(row < NN_ ? ov[mtq][nt][r] : 0.f);
        }
    __syncthreads();

    // === attn-out + residual ===
    {
      const __bf16* aoW = wb + WB_AO + l * 128 * 128;
      const __bf16* Bs[2] = { aoW + ((2 * w) * 16 + c16) * 128, aoW + ((2 * w + 1) * 16 + c16) * 128 };
      f32x4 aa[2][3];
      gemm3xN<2, 4>(xbf, 136, Bs, c16, quad, aa);
#pragma unroll
      for (int nt = 0; nt < 2; ++nt) {
        float ab = ao_b[l * 128 + (2 * w + nt) * 16 + c16];
#pragma unroll
        for (int mt = 0; mt < 3; ++mt)
#pragma unroll
          for (int r = 0; r < 4; ++r) res[mt][nt][r] += aa[nt][mt][r] + ab;
      }
    }
    ln_update(res, ln1_g + l * 128, ln1_b + l * 128, xbf, part, statsA, statsB, tid, w, c16, quad);

    // === FF1 -> hbf (relu, bf16) ===
    {
      const __bf16* f1W = wb + WB_FF1 + l * 256 * 128;
      const __bf16* Bs[4] = { f1W + ((4 * w) * 16 + c16) * 128, f1W + ((4 * w + 1) * 16 + c16) * 128,
                              f1W + ((4 * w + 2) * 16 + c16) * 128, f1W + ((4 * w + 3) * 16 + c16) * 128 };
      f32x4 fa[4][3];
      gemm3xN<4, 4>(xbf, 136, Bs, c16, quad, fa);
#pragma unroll
      for (int nt = 0; nt < 4; ++nt) {
        int col = (4 * w + nt) * 16 + c16;
        float b1 = ff1_b[l * 256 + col];
#pragma unroll
        for (int mt = 0; mt < 3; ++mt)
#pragma unroll
          for (int r = 0; r < 4; ++r) {
            int row = mt * 16 + quad * 4 + r;
            float v = fmaxf(fa[nt][mt][r] + b1, 0.f);
            hbf[row * 264 + col] = (__bf16)(row < NN_ ? v : 0.f);
          }
      }
    }
    __syncthreads();

    // === FF2 + residual ===
    {
      const __bf16* f2W = wb + WB_FF2 + l * 128 * 256;
      const __bf16* Bs[2] = { f2W + ((2 * w) * 16 + c16) * 256, f2W + ((2 * w + 1) * 16 + c16) * 256 };
      f32x4 fa[2][3];
      gemm3xN<2, 8>(hbf, 264, Bs, c16, quad, fa);
#pragma unroll
      for (int nt = 0; nt < 2; ++nt) {
        float fb2 = ff2_b[l * 128 + (2 * w + nt) * 16 + c16];
#pragma unroll
        for (int mt = 0; mt < 3; ++mt)
#pragma unroll
          for (int r = 0; r < 4; ++r) res[mt][nt][r] += fa[nt][mt][r] + fb2;
      }
    }
    ln_update(res, ln2_g + l * 128, ln2_b + l * 128, xbf, part, statsA, statsB, tid, w, c16, quad);
  }

  // ---- stage out: x_final (bf16) -> ws X[f][5376] ----
  {
    __bf16* Xf = Xg + (size_t)f * 5376;
    for (int c = tid; c < 672; c += 256) {
      int row = c >> 4, co = (c & 15) * 8;
      *(bf16x8*)(Xf + row * 128 + co) = ld8(xbf + row * 136 + co);
    }
  }
}

// ---------------- output projection + final LN, K split 4-way across waves ----------------
__global__ __launch_bounds__(1024) void wout_k(const __bf16* __restrict__ X,
                                               const __bf16* __restrict__ Wb,
                                               const float* __restrict__ b_out,
                                               const float* __restrict__ lnf_g,
                                               const float* __restrict__ lnf_b,
                                               float* __restrict__ out) {
  const int blk = blockIdx.x, tid = threadIdx.x;
  const int lane = tid & 63, w2 = tid >> 6, wc = w2 & 3, kh = w2 >> 2;  // wc 0..3, kh 0..3
  const int c16 = lane & 15, quad = lane >> 4;
  __shared__ float cout[64 * 132];
  f32x4 acc0{0,0,0,0}, acc1{0,0,0,0};
  const __bf16* Ar = X + (size_t)(blk * 16 + c16) * 5376 + kh * 1344;
  const __bf16* B0 = Wb + (size_t)((2 * wc) * 16 + c16) * 5376 + kh * 1344;
  const __bf16* B1 = Wb + (size_t)((2 * wc + 1) * 16 + c16) * 5376 + kh * 1344;
#pragma unroll 3
  for (int ks = 0; ks < 42; ++ks) {
    int ko = ks * 32 + quad * 8;
    bf16x8 a = ld8(Ar + ko);
    acc0 = MFMA(a, ld8(B0 + ko), acc0);
    acc1 = MFMA(a, ld8(B1 + ko), acc1);
  }
#pragma unroll
  for (int nt = 0; nt < 2; ++nt) {
    f32x4 a = nt ? acc1 : acc0;
#pragma unroll
    for (int r = 0; r < 4; ++r) cout[(kh * 16 + quad * 4 + r) * 132 + (2 * wc + nt) * 16 + c16] = a[r];
  }
  __syncthreads();
  if (w2 < 4) {
#pragma unroll
    for (int rr = 0; rr < 4; ++rr) {
      int row = w2 * 4 + rr;
      float v0 = cout[row * 132 + lane] + cout[(16 + row) * 132 + lane] +
                 cout[(32 + row) * 132 + lane] + cout[(48 + row) * 132 + lane] + b_out[lane];
      float v1 = cout[row * 132 + 64 + lane] + cout[(16 + row) * 132 + 64 + lane] +
                 cout[(32 + row) * 132 + 64 + lane] + cout[(48 + row) * 132 + 64 + lane] + b_out[64 + lane];
      float s = v0 + v1, ss = v0 * v0 + v1 * v1;
#pragma unroll
      for (int m = 1; m < 64; m <<= 1) { s += __shfl_xor(s, m); ss += __shfl_xor(ss, m); }
      float mu = s * 0.0078125f;
      float var = fmaxf(ss * 0.0078125f - mu * mu, 0.f);
      float rs = rsqrtf(var + 1e-5f);
      size_t o = (size_t)(blk * 16 + row) * 128;
      out[o + lane] = (v0 - mu) * rs * lnf_g[lane] + lnf_b[lane];
      out[o + 64 + lane] = (v1 - mu) * rs * lnf_g[64 + lane] + lnf_b[64 + lane];
    }
  }
}

extern "C" void kernel_launch(void* const* d_in, const int* in_sizes, int n_in,
                              void* d_out, int out_size, void* d_ws, size_t ws_size,
                              hipStream_t stream) {
  const float* forest     = (const float*)d_in[0];
  const int*   adjacency  = (const int*)d_in[1];
  const int*   node_order = (const int*)d_in[2];
  const float* W_in       = (const float*)d_in[3];
  const float* b_in       = (const float*)d_in[4];
  const float* qkv_w      = (const float*)d_in[5];
  const float* qkv_b      = (const float*)d_in[6];
  const float* ao_w       = (const float*)d_in[7];
  const float* ao_b       = (const float*)d_in[8];
  const float* ff1_w      = (const float*)d_in[9];
  const float* ff1_b      = (const float*)d_in[10];
  const float* ff2_w      = (const float*)d_in[11];
  const float* ff2_b      = (const float*)d_in[12];
  const float* ln1_g      = (const float*)d_in[13];
  const float* ln1_b      = (const float*)d_in[14];
  const float* ln2_g      = (const float*)d_in[15];
  const float* ln2_b      = (const float*)d_in[16];
  const float* b_out      = (const float*)d_in[18];
  const float* lnf_g      = (const float*)d_in[19];
  const float* lnf_b      = (const float*)d_in[20];
  __bf16* wb = (__bf16*)d_ws;
  float* out = (float*)d_out;

  prep_bf16<<<dim3(PREP_N / 256), dim3(256), 0, stream>>>(W_in, qkv_w, ao_w, ff1_w, ff2_w,
                                                          (const float*)d_in[17], wb);
  tree_enc<<<dim3(FB_), dim3(256), 0, stream>>>(forest, adjacency, node_order, b_in, qkv_b, ao_b,
                                                ff1_b, ff2_b, ln1_g, ln1_b, ln2_g, ln2_b, wb,
                                                wb + WB_X);
  wout_k<<<dim3(FB_ / 16), dim3(1024), 0, stream>>>(wb + WB_X, wb + WB_WOUT, b_out, lnf_g, lnf_b,
                                                    out);
}

// Round 3
// 499.465 us; speedup vs baseline: 1.2634x; 1.0933x over previous
//
#include <hip/hip_runtime.h>
#include <hip/hip_bf16.h>

typedef __bf16 bf16x8 __attribute__((ext_vector_type(8)));
typedef __bf16 bf16x4 __attribute__((ext_vector_type(4)));
typedef float  f32x4  __attribute__((ext_vector_type(4)));

#define MFMA(a,b,c) __builtin_amdgcn_mfma_f32_16x16x32_bf16((a),(b),(c),0,0,0)

// problem constants
#define NN_  42
#define E_   41
#define FB_  4096
#define SCALE_ 0.17677669529663687f  // 1/sqrt(32)

// ws layout, element offsets into __bf16* ws (layouts preserved == MFMA B-operand layout)
#define WB_WIN  0         // [128][32]
#define WB_QKV  4096      // [L][384][128]
#define WB_AO   102400    // [L][128][128]
#define WB_FF1  135168    // [L][256][128]
#define WB_FF2  200704    // [L][128][256]
#define WB_WOUT 266240    // [128][5376]
#define WB_X    954368    // [4096][5376] staged x_final (bf16)
#define PREP_N  954368

// smem layout (bytes), total 40704.
//  [0,27648)      per-wave qk[48][72] (q cols 0..31, k cols 32..63), w*6912
//                 aliases (lifetime-disjoint):
//                   fbf [48][40]           @0      (init/embed only)
//                   bits int[48][4]        @3840   (init/embed only; pos as bitmask)
//                   adj int[123]           @4608   (init only)
//                   depth int[48]          @5104   (init only)
//                   hbf [48][264]          @0      (FF only; 25344 B)
//                   part float[384]        @25344  (ln_update only; wave3 qk rows 32+ are
//                   statsA/B float[48]     @26880/27072   dead post-scores barrier)
//  [27648,40704)  xbf/obf [48][136] bf16 (aliased; barrier guards swap)
// Register/occupancy ledger (round-2 counters): unified VGPR+AGPR file; arch VGPR=128 +
// ~72 AGPR acc = ~200/wave -> 2 waves/EU -> 2 blocks/CU (22.7% meas). Fix: split qkv
// (72->36 acc) and ff1 (48->24 acc) accumulation passes, then (256,3) budget ~168 total
// fits (est ~110 arch + 36 acc) -> 3 blocks/CU. Round-1 spill signature (WRITE_SIZE
// explosion, VGPR crushed to 84) is the revert trigger.
#define SM_SZ 40704

// ---------------- weight cast to bf16 ----------------
__global__ void prep_bf16(const float* __restrict__ W_in, const float* __restrict__ qkv_w,
                          const float* __restrict__ ao_w, const float* __restrict__ ff1_w,
                          const float* __restrict__ ff2_w, const float* __restrict__ W_out,
                          __bf16* __restrict__ wb) {
  int i = blockIdx.x * 256 + threadIdx.x;
  float v;
  if      (i < 4096)   v = W_in[i];
  else if (i < 102400) v = qkv_w[i - 4096];
  else if (i < 135168) v = ao_w[i - 102400];
  else if (i < 200704) v = ff1_w[i - 135168];
  else if (i < 266240) v = ff2_w[i - 200704];
  else if (i < 954368) v = W_out[i - 266240];
  else return;
  wb[i] = (__bf16)v;
}

__device__ __forceinline__ bf16x8 ld8(const __bf16* p) { return *(const bf16x8*)p; }

__device__ __forceinline__ int pack2(float a, float b) {
  union { __bf16 h[2]; int i; } u;
  u.h[0] = (__bf16)a; u.h[1] = (__bf16)b;
  return u.i;
}

// C = A[48xK] * B^T for NB column-tiles; A in LDS (lda halfwords), B rows contiguous-k (global).
template <int NB, int KS>
__device__ __forceinline__ void gemm3xN(const __bf16* A, int lda, const __bf16* const (&B)[NB],
                                        int c16, int quad, f32x4 (&acc)[NB][3]) {
#pragma unroll
  for (int i = 0; i < NB; ++i) {
    acc[i][0] = f32x4{0,0,0,0}; acc[i][1] = f32x4{0,0,0,0}; acc[i][2] = f32x4{0,0,0,0};
  }
#pragma unroll
  for (int ks = 0; ks < KS; ++ks) {
    int ko = ks * 32 + quad * 8;
    bf16x8 a0 = ld8(A + c16 * lda + ko);
    bf16x8 a1 = ld8(A + (16 + c16) * lda + ko);
    bf16x8 a2 = ld8(A + (32 + c16) * lda + ko);
#pragma unroll
    for (int i = 0; i < NB; ++i) {
      bf16x8 b = ld8(B[i] + ko);
      acc[i][0] = MFMA(a0, b, acc[i][0]);
      acc[i][1] = MFMA(a1, b, acc[i][1]);
      acc[i][2] = MFMA(a2, b, acc[i][2]);
    }
  }
}

// LayerNorm update; res in C-layout (cols (2w+nt)*16+c16); rewrites res + xbf. 3 barriers.
__device__ __forceinline__ void ln_update(float (&res)[3][2][4], const float* __restrict__ g,
                                          const float* __restrict__ bb, __bf16* xbf, float* part,
                                          float* statsA, float* statsB, int tid, int w, int c16,
                                          int quad) {
#pragma unroll
  for (int mt = 0; mt < 3; ++mt)
#pragma unroll
    for (int r = 0; r < 4; ++r) {
      float s = res[mt][0][r] + res[mt][1][r];
      float ss = res[mt][0][r] * res[mt][0][r] + res[mt][1][r] * res[mt][1][r];
      s += __shfl_xor(s, 1); ss += __shfl_xor(ss, 1);
      s += __shfl_xor(s, 2); ss += __shfl_xor(ss, 2);
      s += __shfl_xor(s, 4); ss += __shfl_xor(ss, 4);
      s += __shfl_xor(s, 8); ss += __shfl_xor(ss, 8);
      if (c16 == 0) {
        int row = mt * 16 + quad * 4 + r;
        part[(w * 48 + row) * 2] = s; part[(w * 48 + row) * 2 + 1] = ss;
      }
    }
  __syncthreads();
  if (tid < 48) {
    float S = 0.f, SS = 0.f;
#pragma unroll
    for (int w2 = 0; w2 < 4; ++w2) { S += part[(w2 * 48 + tid) * 2]; SS += part[(w2 * 48 + tid) * 2 + 1]; }
    float mu = S * 0.0078125f;
    float var = fmaxf(SS * 0.0078125f - mu * mu, 0.f);
    statsA[tid] = mu; statsB[tid] = rsqrtf(var + 1e-5f);
  }
  __syncthreads();
  float gg[2], bv[2];
#pragma unroll
  for (int nt = 0; nt < 2; ++nt) { int col = (2 * w + nt) * 16 + c16; gg[nt] = g[col]; bv[nt] = bb[col]; }
#pragma unroll
  for (int mt = 0; mt < 3; ++mt)
#pragma unroll
    for (int r = 0; r < 4; ++r) {
      int row = mt * 16 + quad * 4 + r;
      float mu = statsA[row], rs = statsB[row];
#pragma unroll
      for (int nt = 0; nt < 2; ++nt) {
        float v = (res[mt][nt][r] - mu) * rs * gg[nt] + bv[nt];
        res[mt][nt][r] = v;
        xbf[row * 136 + (2 * w + nt) * 16 + c16] = (__bf16)(row < NN_ ? v : 0.f);
      }
    }
  __syncthreads();
}

// ---------------- per-tree fused encoder: wave-private attention ----------------
__global__ __launch_bounds__(256, 3) void tree_enc(
    const float* __restrict__ forest, const int* __restrict__ adjacency,
    const int* __restrict__ node_order, const float* __restrict__ b_in,
    const float* __restrict__ qkv_b, const float* __restrict__ ao_b,
    const float* __restrict__ ff1_b, const float* __restrict__ ff2_b,
    const float* __restrict__ ln1_g, const float* __restrict__ ln1_b,
    const float* __restrict__ ln2_g, const float* __restrict__ ln2_b,
    const __bf16* __restrict__ wb, __bf16* __restrict__ Xg) {
  const int f = blockIdx.x, tid = threadIdx.x;
  const int lane = tid & 63, w = tid >> 6, c16 = lane & 15, quad = lane >> 4;

  __shared__ alignas(16) unsigned char smem[SM_SZ];
  __bf16* qk     = (__bf16*)(smem + w * 6912);  // per-wave [48][72]: q cols 0..31, k cols 32..63
  __bf16* fbf    = (__bf16*)smem;               // [48][40] (init only)
  __bf16* hbf    = (__bf16*)smem;               // [48][264] (FF only)
  int*    bits_s = (int*)(smem + 3840);         // [48][4] pos bitmask (init/embed only)
  int*    adj_s  = (int*)(smem + 4608);
  int*    depth_s= (int*)(smem + 5104);
  float*  part   = (float*)(smem + 25344);      // ln_update only (qk tail dead then)
  float*  statsA = (float*)(smem + 26880);
  float*  statsB = (float*)(smem + 27072);
  __bf16* xbf    = (__bf16*)(smem + 27648);     // [48][136] x / attn-o (aliased)

  // ---- init phase 1: zeros (fbf + bits), adjacency, depths ----
  for (int i = tid; i < 1152; i += 256) ((int*)smem)[i] = 0;  // fbf [0,3840) + bits [3840,4608)
  if (tid < E_ * 3) adj_s[tid] = adjacency[f * (E_ * 3) + tid];
  if (w == 1) {
    int v = (lane < NN_) ? node_order[f * NN_ + lane] : 0;
    int mx = v;
#pragma unroll
    for (int m = 1; m < 64; m <<= 1) mx = max(mx, __shfl_xor(mx, m));
    if (lane < 48) depth_s[lane] = (lane < NN_) ? (mx - v) : 0;
  }
  __syncthreads();

  // ---- init phase 2: stage forest bf16 + positional walk (bitmask, by depth level) ----
  for (int i = tid; i < NN_ * 32; i += 256) {
    int r = i >> 5, c = i & 31;
    fbf[r * 40 + c] = (__bf16)forest[f * (NN_ * 32) + i];
  }
  if (w == 0) {
    // one edge per lane; process levels in parallel. pos values are 0/1 at distinct
    // indices (distinct ancestor depths) => 128-bit OR mask per node == the sum.
    int pl = -1, cl = 0, pd = 0, idx = 0;
    if (lane < E_) {
      int p = adj_s[lane * 3], c = adj_s[lane * 3 + 1], s = adj_s[lane * 3 + 2];
      if (p >= 0 && c >= 0) {
        pl = p - f * NN_; cl = c - f * NN_;
        int si = s + 1; si = si < 0 ? 0 : (si > 2 ? 2 : si);
        pd = depth_s[pl]; idx = pd * 3 + si;
      }
    }
    int dv = (lane < NN_) ? depth_s[lane] : 0;
#pragma unroll
    for (int m = 1; m < 64; m <<= 1) dv = max(dv, __shfl_xor(dv, m));
    int plc = pl < 0 ? 0 : pl;
    int bm = 1 << (idx & 31), wi = idx >> 5;
    int m0 = (wi == 0) ? bm : 0, m1 = (wi == 1) ? bm : 0;
    int m2 = (wi == 2) ? bm : 0, m3 = (wi == 3) ? bm : 0;
    for (int d = 0; d < dv; ++d) {
      int4 pb = *(int4*)&bits_s[plc * 4];
      if (pl >= 0 && pd == d) {
        int4 nb;
        nb.x = pb.x | m0; nb.y = pb.y | m1; nb.z = pb.z | m2; nb.w = pb.w | m3;
        *(int4*)&bits_s[cl * 4] = nb;
      }
      asm volatile("s_waitcnt lgkmcnt(0)" ::: "memory");
    }
  }
  __syncthreads();

  // ---- embed: x0 = forest @ W_in^T + b_in + pos ----
  float res[3][2][4];
  {
    const __bf16* Bw[2] = { wb + WB_WIN + ((2 * w) * 16 + c16) * 32,
                            wb + WB_WIN + ((2 * w + 1) * 16 + c16) * 32 };
    f32x4 ea[2][3];
    gemm3xN<2, 1>(fbf, 40, Bw, c16, quad, ea);
#pragma unroll
    for (int nt = 0; nt < 2; ++nt) {
      int col = (2 * w + nt) * 16 + c16;
      float bi = b_in[col];
      int wsel = col >> 5, shv = col & 31;
#pragma unroll
      for (int mt = 0; mt < 3; ++mt)
#pragma unroll
        for (int r = 0; r < 4; ++r) {
          int row = mt * 16 + quad * 4 + r;
          float v = ea[nt][mt][r] + bi + (float)((bits_s[row * 4 + wsel] >> shv) & 1);
          res[mt][nt][r] = v;
          xbf[row * 136 + col] = (__bf16)(row < NN_ ? v : 0.f);
        }
    }
  }
  __syncthreads();

  // ---- encoder layers ----
  for (int l = 0; l < 2; ++l) {
    // === per-wave qkv GEMM, head h = w; two 3-tile passes (peak acc 36 not 72) ===
    int vp[2][3][2];  // [s = d-half][node m-tile][node pair]: V[mt*16+quad*4+2h..+1][s*16+c16]
    {
      const __bf16* qkvW = wb + WB_QKV + l * 384 * 128;
      const float* qbl = qkv_b + l * 384;
#pragma unroll
      for (int pass = 0; pass < 2; ++pass) {
        f32x4 qa[3][3];
#pragma unroll
        for (int j = 0; j < 3; ++j) { qa[j][0] = f32x4{0,0,0,0}; qa[j][1] = f32x4{0,0,0,0}; qa[j][2] = f32x4{0,0,0,0}; }
        const __bf16* Bp[3];
#pragma unroll
        for (int j = 0; j < 3; ++j) {
          int t = pass * 3 + j, p = t >> 1, s = t & 1;
          Bp[j] = qkvW + (p * 128 + w * 32 + s * 16 + c16) * 128;
        }
#pragma unroll
        for (int ks = 0; ks < 4; ++ks) {
          int ko = ks * 32 + quad * 8;
          bf16x8 a0 = ld8(xbf + c16 * 136 + ko);
          bf16x8 a1 = ld8(xbf + (16 + c16) * 136 + ko);
          bf16x8 a2 = ld8(xbf + (32 + c16) * 136 + ko);
#pragma unroll
          for (int j = 0; j < 3; ++j) {
            bf16x8 b = ld8(Bp[j] + ko);
            qa[j][0] = MFMA(a0, b, qa[j][0]);
            qa[j][1] = MFMA(a1, b, qa[j][1]);
            qa[j][2] = MFMA(a2, b, qa[j][2]);
          }
        }
#pragma unroll
        for (int j = 0; j < 3; ++j) {
          int t = pass * 3 + j, p = t >> 1, s = t & 1;
          float bias = qbl[p * 128 + w * 32 + s * 16 + c16];
#pragma unroll
          for (int mt = 0; mt < 3; ++mt) {
            if (p == 2) {  // V -> registers (bf16 pair-packed), no LDS round-trip
              vp[s][mt][0] = pack2(qa[j][mt][0] + bias, qa[j][mt][1] + bias);
              vp[s][mt][1] = pack2(qa[j][mt][2] + bias, qa[j][mt][3] + bias);
            } else {       // Q (scaled) / K -> qk[node][col]
              int colo = (p == 0 ? 0 : 32) + s * 16 + c16;
#pragma unroll
              for (int r = 0; r < 4; ++r) {
                float v = qa[j][mt][r] + bias;
                if (p == 0) v *= SCALE_;
                qk[(mt * 16 + quad * 4 + r) * 72 + colo] = (__bf16)v;
              }
            }
          }
        }
      }
    }
    __syncthreads();  // guards xbf reads (qkv) vs obf writes (PV) across waves

    // === scores S^T = K Q^T, 9 tiles in-register ===
    f32x4 st[3][3];
    {
      bf16x8 ka[3], qb2[3];
#pragma unroll
      for (int m = 0; m < 3; ++m) ka[m] = ld8(qk + (m * 16 + c16) * 72 + 32 + quad * 8);
#pragma unroll
      for (int n = 0; n < 3; ++n) qb2[n] = ld8(qk + (n * 16 + c16) * 72 + quad * 8);
#pragma unroll
      for (int m = 0; m < 3; ++m)
#pragma unroll
        for (int n = 0; n < 3; ++n) {
          f32x4 z{0,0,0,0};
          st[m][n] = MFMA(ka[m], qb2[n], z);
        }
    }

    // === softmax fully in-register (query = n-tile*16 + c16; keys on quad/reg) ===
    int dwp[3][3][2];  // packed P bf16 pairs [key-tile][query-tile][dword]
#pragma unroll
    for (int n = 0; n < 3; ++n) {
      float mx = -3.0e38f;
#pragma unroll
      for (int m = 0; m < 3; ++m)
#pragma unroll
        for (int r = 0; r < 4; ++r) {
          bool valid = (m < 2) || (quad * 4 + r < 10);  // key < 42
          mx = fmaxf(mx, valid ? st[m][n][r] : -3.0e38f);
        }
      mx = fmaxf(mx, __shfl_xor(mx, 16));
      mx = fmaxf(mx, __shfl_xor(mx, 32));
      float sm = 0.f, ev[3][4];
#pragma unroll
      for (int m = 0; m < 3; ++m)
#pragma unroll
        for (int r = 0; r < 4; ++r) {
          bool valid = (m < 2) || (quad * 4 + r < 10);
          float e = valid ? __expf(st[m][n][r] - mx) : 0.f;
          ev[m][r] = e; sm += e;
        }
      sm += __shfl_xor(sm, 16);
      sm += __shfl_xor(sm, 32);
      float inv = 1.f / sm;
#pragma unroll
      for (int m = 0; m < 3; ++m) {
        dwp[m][n][0] = pack2(ev[m][0] * inv, ev[m][1] * inv);
        dwp[m][n][1] = pack2(ev[m][2] * inv, ev[m][3] * inv);
      }
    }

    // === PV: both P and V^T fragments via shuffle-transpose (no LDS round-trip) ===
    f32x4 ov[3][2];
#pragma unroll
    for (int mtq = 0; mtq < 3; ++mtq) { ov[mtq][0] = f32x4{0,0,0,0}; ov[mtq][1] = f32x4{0,0,0,0}; }
    int sl0 = (2 * (quad & 1)) * 16 + c16, sl1 = sl0 + 16;
    bool hi = quad > 1;
#pragma unroll
    for (int ks = 0; ks < 2; ++ks) {
      // B-operand: V[g..g+7][d=nt*16+c16], g = koB(quad). dword m holds nodes (g+2m, g+2m+1):
      //   src lane = (((quad<<1)+(m>>1))&3)*16 + c16, reg = vp[nt][mt_src][m&1],
      //   mt_src = quad>>1 (ks=0) | 2 (ks=1).  Matches A-operand koB exactly (A=0 there).
      bf16x8 bv[2];
#pragma unroll
      for (int nt = 0; nt < 2; ++nt) {
        union { int i[4]; bf16x8 v; } U;
#pragma unroll
        for (int m = 0; m < 4; ++m) {
          int srcl = (((quad << 1) + (m >> 1)) & 3) * 16 + c16;
          if (ks == 0) {
            int x0 = __shfl(vp[nt][0][m & 1], srcl);
            int x1 = __shfl(vp[nt][1][m & 1], srcl);
            U.i[m] = (quad >> 1) ? x1 : x0;
          } else {
            U.i[m] = __shfl(vp[nt][2][m & 1], srcl);
          }
        }
        bv[nt] = U.v;
      }
      int lo = 2 * ks;
#pragma unroll
      for (int mtq = 0; mtq < 3; ++mtq) {
        int a0 = __shfl(dwp[lo][mtq][0], sl0), a1 = __shfl(dwp[lo][mtq][1], sl0);
        int a2 = __shfl(dwp[lo][mtq][0], sl1), a3 = __shfl(dwp[lo][mtq][1], sl1);
        int b0 = 0, b1 = 0, b2 = 0, b3 = 0;
        if (ks == 0) {
          b0 = __shfl(dwp[1][mtq][0], sl0); b1 = __shfl(dwp[1][mtq][1], sl0);
          b2 = __shfl(dwp[1][mtq][0], sl1); b3 = __shfl(dwp[1][mtq][1], sl1);
        }
        union { int i[4]; bf16x8 v; } A;
        A.i[0] = hi ? b0 : a0; A.i[1] = hi ? b1 : a1;
        A.i[2] = hi ? b2 : a2; A.i[3] = hi ? b3 : a3;
        ov[mtq][0] = MFMA(A.v, bv[0], ov[mtq][0]);
        ov[mtq][1] = MFMA(A.v, bv[1], ov[mtq][1]);
      }
    }
    // obf (= xbf alias) write: head slab cols w*32..w*32+31
#pragma unroll
    for (int mtq = 0; mtq < 3; ++mtq)
#pragma unroll
      for (int nt = 0; nt < 2; ++nt)
#pragma unroll
        for (int r = 0; r < 4; ++r) {
          int row = mtq * 16 + quad * 4 + r;
          xbf[row * 136 + w * 32 + nt * 16 + c16] = (__bf16)(row < NN_ ? ov[mtq][nt][r] : 0.f);
        }
    __syncthreads();

    // === attn-out + residual ===
    {
      const __bf16* aoW = wb + WB_AO + l * 128 * 128;
      const __bf16* Bs[2] = { aoW + ((2 * w) * 16 + c16) * 128, aoW + ((2 * w + 1) * 16 + c16) * 128 };
      f32x4 aa[2][3];
      gemm3xN<2, 4>(xbf, 136, Bs, c16, quad, aa);
#pragma unroll
      for (int nt = 0; nt < 2; ++nt) {
        float ab = ao_b[l * 128 + (2 * w + nt) * 16 + c16];
#pragma unroll
        for (int mt = 0; mt < 3; ++mt)
#pragma unroll
          for (int r = 0; r < 4; ++r) res[mt][nt][r] += aa[nt][mt][r] + ab;
      }
    }
    ln_update(res, ln1_g + l * 128, ln1_b + l * 128, xbf, part, statsA, statsB, tid, w, c16, quad);

    // === FF1 -> hbf (relu, bf16); two 2-tile passes (peak acc 24 not 48) ===
    {
      const __bf16* f1W = wb + WB_FF1 + l * 256 * 128;
#pragma unroll
      for (int pass = 0; pass < 2; ++pass) {
        const __bf16* Bs[2] = { f1W + ((4 * w + 2 * pass) * 16 + c16) * 128,
                                f1W + ((4 * w + 2 * pass + 1) * 16 + c16) * 128 };
        f32x4 fa[2][3];
        gemm3xN<2, 4>(xbf, 136, Bs, c16, quad, fa);
#pragma unroll
        for (int j = 0; j < 2; ++j) {
          int nt = 2 * pass + j;
          int col = (4 * w + nt) * 16 + c16;
          float b1 = ff1_b[l * 256 + col];
#pragma unroll
          for (int mt = 0; mt < 3; ++mt)
#pragma unroll
            for (int r = 0; r < 4; ++r) {
              int row = mt * 16 + quad * 4 + r;
              float v = fmaxf(fa[j][mt][r] + b1, 0.f);
              hbf[row * 264 + col] = (__bf16)(row < NN_ ? v : 0.f);
            }
        }
      }
    }
    __syncthreads();

    // === FF2 + residual ===
    {
      const __bf16* f2W = wb + WB_FF2 + l * 128 * 256;
      const __bf16* Bs[2] = { f2W + ((2 * w) * 16 + c16) * 256, f2W + ((2 * w + 1) * 16 + c16) * 256 };
      f32x4 fa[2][3];
      gemm3xN<2, 8>(hbf, 264, Bs, c16, quad, fa);
#pragma unroll
      for (int nt = 0; nt < 2; ++nt) {
        float fb2 = ff2_b[l * 128 + (2 * w + nt) * 16 + c16];
#pragma unroll
        for (int mt = 0; mt < 3; ++mt)
#pragma unroll
          for (int r = 0; r < 4; ++r) res[mt][nt][r] += fa[nt][mt][r] + fb2;
      }
    }
    ln_update(res, ln2_g + l * 128, ln2_b + l * 128, xbf, part, statsA, statsB, tid, w, c16, quad);
  }

  // ---- stage out: x_final (bf16) -> ws X[f][5376] ----
  {
    __bf16* Xf = Xg + (size_t)f * 5376;
    for (int c = tid; c < 672; c += 256) {
      int row = c >> 4, co = (c & 15) * 8;
      *(bf16x8*)(Xf + row * 128 + co) = ld8(xbf + row * 136 + co);
    }
  }
}

// ---------------- output projection + final LN, K split 4-way across waves ----------------
__global__ __launch_bounds__(1024) void wout_k(const __bf16* __restrict__ X,
                                               const __bf16* __restrict__ Wb,
                                               const float* __restrict__ b_out,
                                               const float* __restrict__ lnf_g,
                                               const float* __restrict__ lnf_b,
                                               float* __restrict__ out) {
  const int blk = blockIdx.x, tid = threadIdx.x;
  const int lane = tid & 63, w2 = tid >> 6, wc = w2 & 3, kh = w2 >> 2;  // wc 0..3, kh 0..3
  const int c16 = lane & 15, quad = lane >> 4;
  __shared__ float cout[64 * 132];
  f32x4 acc0{0,0,0,0}, acc1{0,0,0,0};
  const __bf16* Ar = X + (size_t)(blk * 16 + c16) * 5376 + kh * 1344;
  const __bf16* B0 = Wb + (size_t)((2 * wc) * 16 + c16) * 5376 + kh * 1344;
  const __bf16* B1 = Wb + (size_t)((2 * wc + 1) * 16 + c16) * 5376 + kh * 1344;
#pragma unroll 3
  for (int ks = 0; ks < 42; ++ks) {
    int ko = ks * 32 + quad * 8;
    bf16x8 a = ld8(Ar + ko);
    acc0 = MFMA(a, ld8(B0 + ko), acc0);
    acc1 = MFMA(a, ld8(B1 + ko), acc1);
  }
#pragma unroll
  for (int nt = 0; nt < 2; ++nt) {
    f32x4 a = nt ? acc1 : acc0;
#pragma unroll
    for (int r = 0; r < 4; ++r) cout[(kh * 16 + quad * 4 + r) * 132 + (2 * wc + nt) * 16 + c16] = a[r];
  }
  __syncthreads();
  if (w2 < 4) {
#pragma unroll
    for (int rr = 0; rr < 4; ++rr) {
      int row = w2 * 4 + rr;
      float v0 = cout[row * 132 + lane] + cout[(16 + row) * 132 + lane] +
                 cout[(32 + row) * 132 + lane] + cout[(48 + row) * 132 + lane] + b_out[lane];
      float v1 = cout[row * 132 + 64 + lane] + cout[(16 + row) * 132 + 64 + lane] +
                 cout[(32 + row) * 132 + 64 + lane] + cout[(48 + row) * 132 + 64 + lane] + b_out[64 + lane];
      float s = v0 + v1, ss = v0 * v0 + v1 * v1;
#pragma unroll
      for (int m = 1; m < 64; m <<= 1) { s += __shfl_xor(s, m); ss += __shfl_xor(ss, m); }
      float mu = s * 0.0078125f;
      float var = fmaxf(ss * 0.0078125f - mu * mu, 0.f);
      float rs = rsqrtf(var + 1e-5f);
      size_t o = (size_t)(blk * 16 + row) * 128;
      out[o + lane] = (v0 - mu) * rs * lnf_g[lane] + lnf_b[lane];
      out[o + 64 + lane] = (v1 - mu) * rs * lnf_g[64 + lane] + lnf_b[64 + lane];
    }
  }
}

extern "C" void kernel_launch(void* const* d_in, const int* in_sizes, int n_in,
                              void* d_out, int out_size, void* d_ws, size_t ws_size,
                              hipStream_t stream) {
  const float* forest     = (const float*)d_in[0];
  const int*   adjacency  = (const int*)d_in[1];
  const int*   node_order = (const int*)d_in[2];
  const float* W_in       = (const float*)d_in[3];
  const float* b_in       = (const float*)d_in[4];
  const float* qkv_w      = (const float*)d_in[5];
  const float* qkv_b      = (const float*)d_in[6];
  const float* ao_w       = (const float*)d_in[7];
  const float* ao_b       = (const float*)d_in[8];
  const float* ff1_w      = (const float*)d_in[9];
  const float* ff1_b      = (const float*)d_in[10];
  const float* ff2_w      = (const float*)d_in[11];
  const float* ff2_b      = (const float*)d_in[12];
  const float* ln1_g      = (const float*)d_in[13];
  const float* ln1_b      = (const float*)d_in[14];
  const float* ln2_g      = (const float*)d_in[15];
  const float* ln2_b      = (const float*)d_in[16];
  const float* b_out      = (const float*)d_in[18];
  const float* lnf_g      = (const float*)d_in[19];
  const float* lnf_b      = (const float*)d_in[20];
  __bf16* wb = (__bf16*)d_ws;
  float* out = (float*)d_out;

  prep_bf16<<<dim3(PREP_N / 256), dim3(256), 0, stream>>>(W_in, qkv_w, ao_w, ff1_w, ff2_w,
                                                          (const float*)d_in[17], wb);
  tree_enc<<<dim3(FB_), dim3(256), 0, stream>>>(forest, adjacency, node_order, b_in, qkv_b, ao_b,
                                                ff1_b, ff2_b, ln1_g, ln1_b, ln2_g, ln2_b, wb,
                                                wb + WB_X);
  wout_k<<<dim3(FB_ / 16), dim3(1024), 0, stream>>>(wb + WB_X, wb + WB_WOUT, b_out, lnf_g, lnf_b,
                                                    out);
}

// Round 4
// 482.744 us; speedup vs baseline: 1.3072x; 1.0346x over previous
//
#include <hip/hip_runtime.h>
#include <hip/hip_bf16.h>

typedef __bf16 bf16x8 __attribute__((ext_vector_type(8)));
typedef __bf16 bf16x4 __attribute__((ext_vector_type(4)));
typedef float  f32x4  __attribute__((ext_vector_type(4)));

#define MFMA(a,b,c) __builtin_amdgcn_mfma_f32_16x16x32_bf16((a),(b),(c),0,0,0)

// problem constants
#define NN_  42
#define E_   41
#define FB_  4096
#define SCALE_ 0.17677669529663687f  // 1/sqrt(32)

// ws layout, element offsets into __bf16* ws (layouts preserved == MFMA B-operand layout)
#define WB_WIN  0         // [128][32]
#define WB_QKV  4096      // [L][384][128]
#define WB_AO   102400    // [L][128][128]
#define WB_FF1  135168    // [L][256][128]
#define WB_FF2  200704    // [L][128][256]
#define WB_WOUT 266240    // [128][5376]
#define WB_X    954368    // [4096][5376] staged x_final (bf16)
#define PREP_N  954368

// smem layout (bytes), total 48384 -> 3 blocks/CU (145152 <= 163840).
// Bank-conflict design: all tile row strides are ==12 mod 32 dwords AND 16B-aligned
// (qk 88hw=44dw, xbf 152hw=76dw, hbf 280hw=140dw). 16-row x 4-quad ds_read_b128 then
// only aliases rows 8 apart (2-way, free per m136); the old ==4 mod 32 strides were
// 4-way on every GEMM read + Q/K store (1.61e7 conflict cycles in round-3 PMC).
//  [0,33792)      per-wave qk[48][88] (q cols 0..31, k cols 32..63), w*8448
//                 aliases (lifetime-disjoint):
//                   fbf [48][40]           @0      (init/embed only)
//                   bits int[48][4]        @3840   (init/embed only; pos as bitmask)
//                   adj int[123]           @4608   (init only)
//                   depth int[48]          @5104   (init only)
//                   hbf [48][280]          @0      (FF only; 26880 B)
//                   part float[384]        @26880  (ln_update only; disjoint from hbf,
//                   statsA/B float[48]     @28416/28608   wave-3 qk dead post-scores)
//  [33792,48384)  xbf/obf [48][152] bf16 (aliased; barrier guards swap)
// Register ledger: round-3 at (256,3) hit budget exactly (VGPR=84 arch + ~86 acc) and
// spilled ~19MB/dispatch (WRITE_SIZE 44->63MB). qkv split 2x3-tile -> 3x2-tile passes
// (acc 36->24) to fit without spill. Round-1 spill signature (WRITE explosion, VGPR
// crushed) remains the revert trigger.
#define SM_SZ 48384

// ---------------- weight cast to bf16 ----------------
__global__ void prep_bf16(const float* __restrict__ W_in, const float* __restrict__ qkv_w,
                          const float* __restrict__ ao_w, const float* __restrict__ ff1_w,
                          const float* __restrict__ ff2_w, const float* __restrict__ W_out,
                          __bf16* __restrict__ wb) {
  int i = blockIdx.x * 256 + threadIdx.x;
  float v;
  if      (i < 4096)   v = W_in[i];
  else if (i < 102400) v = qkv_w[i - 4096];
  else if (i < 135168) v = ao_w[i - 102400];
  else if (i < 200704) v = ff1_w[i - 135168];
  else if (i < 266240) v = ff2_w[i - 200704];
  else if (i < 954368) v = W_out[i - 266240];
  else return;
  wb[i] = (__bf16)v;
}

__device__ __forceinline__ bf16x8 ld8(const __bf16* p) { return *(const bf16x8*)p; }

__device__ __forceinline__ int pack2(float a, float b) {
  union { __bf16 h[2]; int i; } u;
  u.h[0] = (__bf16)a; u.h[1] = (__bf16)b;
  return u.i;
}

// C = A[48xK] * B^T for NB column-tiles; A in LDS (lda halfwords), B rows contiguous-k (global).
template <int NB, int KS>
__device__ __forceinline__ void gemm3xN(const __bf16* A, int lda, const __bf16* const (&B)[NB],
                                        int c16, int quad, f32x4 (&acc)[NB][3]) {
#pragma unroll
  for (int i = 0; i < NB; ++i) {
    acc[i][0] = f32x4{0,0,0,0}; acc[i][1] = f32x4{0,0,0,0}; acc[i][2] = f32x4{0,0,0,0};
  }
#pragma unroll
  for (int ks = 0; ks < KS; ++ks) {
    int ko = ks * 32 + quad * 8;
    bf16x8 a0 = ld8(A + c16 * lda + ko);
    bf16x8 a1 = ld8(A + (16 + c16) * lda + ko);
    bf16x8 a2 = ld8(A + (32 + c16) * lda + ko);
#pragma unroll
    for (int i = 0; i < NB; ++i) {
      bf16x8 b = ld8(B[i] + ko);
      acc[i][0] = MFMA(a0, b, acc[i][0]);
      acc[i][1] = MFMA(a1, b, acc[i][1]);
      acc[i][2] = MFMA(a2, b, acc[i][2]);
    }
  }
}

// LayerNorm update; res in C-layout (cols (2w+nt)*16+c16); rewrites res + xbf. 3 barriers.
__device__ __forceinline__ void ln_update(float (&res)[3][2][4], const float* __restrict__ g,
                                          const float* __restrict__ bb, __bf16* xbf, float* part,
                                          float* statsA, float* statsB, int tid, int w, int c16,
                                          int quad) {
#pragma unroll
  for (int mt = 0; mt < 3; ++mt)
#pragma unroll
    for (int r = 0; r < 4; ++r) {
      float s = res[mt][0][r] + res[mt][1][r];
      float ss = res[mt][0][r] * res[mt][0][r] + res[mt][1][r] * res[mt][1][r];
      s += __shfl_xor(s, 1); ss += __shfl_xor(ss, 1);
      s += __shfl_xor(s, 2); ss += __shfl_xor(ss, 2);
      s += __shfl_xor(s, 4); ss += __shfl_xor(ss, 4);
      s += __shfl_xor(s, 8); ss += __shfl_xor(ss, 8);
      if (c16 == 0) {
        int row = mt * 16 + quad * 4 + r;
        part[(w * 48 + row) * 2] = s; part[(w * 48 + row) * 2 + 1] = ss;
      }
    }
  __syncthreads();
  if (tid < 48) {
    float S = 0.f, SS = 0.f;
#pragma unroll
    for (int w2 = 0; w2 < 4; ++w2) { S += part[(w2 * 48 + tid) * 2]; SS += part[(w2 * 48 + tid) * 2 + 1]; }
    float mu = S * 0.0078125f;
    float var = fmaxf(SS * 0.0078125f - mu * mu, 0.f);
    statsA[tid] = mu; statsB[tid] = rsqrtf(var + 1e-5f);
  }
  __syncthreads();
  float gg[2], bv[2];
#pragma unroll
  for (int nt = 0; nt < 2; ++nt) { int col = (2 * w + nt) * 16 + c16; gg[nt] = g[col]; bv[nt] = bb[col]; }
#pragma unroll
  for (int mt = 0; mt < 3; ++mt)
#pragma unroll
    for (int r = 0; r < 4; ++r) {
      int row = mt * 16 + quad * 4 + r;
      float mu = statsA[row], rs = statsB[row];
#pragma unroll
      for (int nt = 0; nt < 2; ++nt) {
        float v = (res[mt][nt][r] - mu) * rs * gg[nt] + bv[nt];
        res[mt][nt][r] = v;
        xbf[row * 152 + (2 * w + nt) * 16 + c16] = (__bf16)(row < NN_ ? v : 0.f);
      }
    }
  __syncthreads();
}

// ---------------- per-tree fused encoder: wave-private attention ----------------
__global__ __launch_bounds__(256, 3) void tree_enc(
    const float* __restrict__ forest, const int* __restrict__ adjacency,
    const int* __restrict__ node_order, const float* __restrict__ b_in,
    const float* __restrict__ qkv_b, const float* __restrict__ ao_b,
    const float* __restrict__ ff1_b, const float* __restrict__ ff2_b,
    const float* __restrict__ ln1_g, const float* __restrict__ ln1_b,
    const float* __restrict__ ln2_g, const float* __restrict__ ln2_b,
    const __bf16* __restrict__ wb, __bf16* __restrict__ Xg) {
  const int f = blockIdx.x, tid = threadIdx.x;
  const int lane = tid & 63, w = tid >> 6, c16 = lane & 15, quad = lane >> 4;

  __shared__ alignas(16) unsigned char smem[SM_SZ];
  __bf16* qk     = (__bf16*)(smem + w * 8448);  // per-wave [48][88]: q cols 0..31, k cols 32..63
  __bf16* fbf    = (__bf16*)smem;               // [48][40] (init only)
  __bf16* hbf    = (__bf16*)smem;               // [48][280] (FF only)
  int*    bits_s = (int*)(smem + 3840);         // [48][4] pos bitmask (init/embed only)
  int*    adj_s  = (int*)(smem + 4608);
  int*    depth_s= (int*)(smem + 5104);
  float*  part   = (float*)(smem + 26880);      // ln_update only (disjoint from hbf)
  float*  statsA = (float*)(smem + 28416);
  float*  statsB = (float*)(smem + 28608);
  __bf16* xbf    = (__bf16*)(smem + 33792);     // [48][152] x / attn-o (aliased)

  // ---- init phase 1: zeros (fbf + bits), adjacency, depths ----
  for (int i = tid; i < 1152; i += 256) ((int*)smem)[i] = 0;  // fbf [0,3840) + bits [3840,4608)
  if (tid < E_ * 3) adj_s[tid] = adjacency[f * (E_ * 3) + tid];
  if (w == 1) {
    int v = (lane < NN_) ? node_order[f * NN_ + lane] : 0;
    int mx = v;
#pragma unroll
    for (int m = 1; m < 64; m <<= 1) mx = max(mx, __shfl_xor(mx, m));
    if (lane < 48) depth_s[lane] = (lane < NN_) ? (mx - v) : 0;
  }
  __syncthreads();

  // ---- init phase 2: stage forest bf16 + positional walk (bitmask, by depth level) ----
  for (int i = tid; i < NN_ * 32; i += 256) {
    int r = i >> 5, c = i & 31;
    fbf[r * 40 + c] = (__bf16)forest[f * (NN_ * 32) + i];
  }
  if (w == 0) {
    // one edge per lane; process levels in parallel. pos values are 0/1 at distinct
    // indices (distinct ancestor depths) => 128-bit OR mask per node == the sum.
    int pl = -1, cl = 0, pd = 0, idx = 0;
    if (lane < E_) {
      int p = adj_s[lane * 3], c = adj_s[lane * 3 + 1], s = adj_s[lane * 3 + 2];
      if (p >= 0 && c >= 0) {
        pl = p - f * NN_; cl = c - f * NN_;
        int si = s + 1; si = si < 0 ? 0 : (si > 2 ? 2 : si);
        pd = depth_s[pl]; idx = pd * 3 + si;
      }
    }
    int dv = (lane < NN_) ? depth_s[lane] : 0;
#pragma unroll
    for (int m = 1; m < 64; m <<= 1) dv = max(dv, __shfl_xor(dv, m));
    int plc = pl < 0 ? 0 : pl;
    int bm = 1 << (idx & 31), wi = idx >> 5;
    int m0 = (wi == 0) ? bm : 0, m1 = (wi == 1) ? bm : 0;
    int m2 = (wi == 2) ? bm : 0, m3 = (wi == 3) ? bm : 0;
    for (int d = 0; d < dv; ++d) {
      int4 pb = *(int4*)&bits_s[plc * 4];
      if (pl >= 0 && pd == d) {
        int4 nb;
        nb.x = pb.x | m0; nb.y = pb.y | m1; nb.z = pb.z | m2; nb.w = pb.w | m3;
        *(int4*)&bits_s[cl * 4] = nb;
      }
      asm volatile("s_waitcnt lgkmcnt(0)" ::: "memory");
    }
  }
  __syncthreads();

  // ---- embed: x0 = forest @ W_in^T + b_in + pos ----
  float res[3][2][4];
  {
    const __bf16* Bw[2] = { wb + WB_WIN + ((2 * w) * 16 + c16) * 32,
                            wb + WB_WIN + ((2 * w + 1) * 16 + c16) * 32 };
    f32x4 ea[2][3];
    gemm3xN<2, 1>(fbf, 40, Bw, c16, quad, ea);
#pragma unroll
    for (int nt = 0; nt < 2; ++nt) {
      int col = (2 * w + nt) * 16 + c16;
      float bi = b_in[col];
      int wsel = col >> 5, shv = col & 31;
#pragma unroll
      for (int mt = 0; mt < 3; ++mt)
#pragma unroll
        for (int r = 0; r < 4; ++r) {
          int row = mt * 16 + quad * 4 + r;
          float v = ea[nt][mt][r] + bi + (float)((bits_s[row * 4 + wsel] >> shv) & 1);
          res[mt][nt][r] = v;
          xbf[row * 152 + col] = (__bf16)(row < NN_ ? v : 0.f);
        }
    }
  }
  __syncthreads();

  // ---- encoder layers ----
  for (int l = 0; l < 2; ++l) {
    // === per-wave qkv GEMM, head h = w; three 2-tile passes (Q, K, V; peak acc 24) ===
    int vp[2][3][2];  // [s = d-half][node m-tile][node pair]: V[mt*16+quad*4+2h..+1][s*16+c16]
    {
      const __bf16* qkvW = wb + WB_QKV + l * 384 * 128;
      const float* qbl = qkv_b + l * 384;
#pragma unroll
      for (int p = 0; p < 3; ++p) {  // 0=Q, 1=K, 2=V
        f32x4 qa[2][3];
#pragma unroll
        for (int j = 0; j < 2; ++j) { qa[j][0] = f32x4{0,0,0,0}; qa[j][1] = f32x4{0,0,0,0}; qa[j][2] = f32x4{0,0,0,0}; }
        const __bf16* Bp[2];
#pragma unroll
        for (int j = 0; j < 2; ++j)
          Bp[j] = qkvW + (p * 128 + w * 32 + j * 16 + c16) * 128;
#pragma unroll
        for (int ks = 0; ks < 4; ++ks) {
          int ko = ks * 32 + quad * 8;
          bf16x8 a0 = ld8(xbf + c16 * 152 + ko);
          bf16x8 a1 = ld8(xbf + (16 + c16) * 152 + ko);
          bf16x8 a2 = ld8(xbf + (32 + c16) * 152 + ko);
#pragma unroll
          for (int j = 0; j < 2; ++j) {
            bf16x8 b = ld8(Bp[j] + ko);
            qa[j][0] = MFMA(a0, b, qa[j][0]);
            qa[j][1] = MFMA(a1, b, qa[j][1]);
            qa[j][2] = MFMA(a2, b, qa[j][2]);
          }
        }
#pragma unroll
        for (int j = 0; j < 2; ++j) {
          float bias = qbl[p * 128 + w * 32 + j * 16 + c16];
#pragma unroll
          for (int mt = 0; mt < 3; ++mt) {
            if (p == 2) {  // V -> registers (bf16 pair-packed), no LDS round-trip
              vp[j][mt][0] = pack2(qa[j][mt][0] + bias, qa[j][mt][1] + bias);
              vp[j][mt][1] = pack2(qa[j][mt][2] + bias, qa[j][mt][3] + bias);
            } else {       // Q (scaled) / K -> qk[node][col]
              int colo = (p == 0 ? 0 : 32) + j * 16 + c16;
#pragma unroll
              for (int r = 0; r < 4; ++r) {
                float v = qa[j][mt][r] + bias;
                if (p == 0) v *= SCALE_;
                qk[(mt * 16 + quad * 4 + r) * 88 + colo] = (__bf16)v;
              }
            }
          }
        }
      }
    }
    __syncthreads();  // guards xbf reads (qkv) vs obf writes (PV) across waves

    // === scores S^T = K Q^T, 9 tiles in-register ===
    f32x4 st[3][3];
    {
      bf16x8 ka[3], qb2[3];
#pragma unroll
      for (int m = 0; m < 3; ++m) ka[m] = ld8(qk + (m * 16 + c16) * 88 + 32 + quad * 8);
#pragma unroll
      for (int n = 0; n < 3; ++n) qb2[n] = ld8(qk + (n * 16 + c16) * 88 + quad * 8);
#pragma unroll
      for (int m = 0; m < 3; ++m)
#pragma unroll
        for (int n = 0; n < 3; ++n) {
          f32x4 z{0,0,0,0};
          st[m][n] = MFMA(ka[m], qb2[n], z);
        }
    }

    // === softmax fully in-register (query = n-tile*16 + c16; keys on quad/reg) ===
    int dwp[3][3][2];  // packed P bf16 pairs [key-tile][query-tile][dword]
#pragma unroll
    for (int n = 0; n < 3; ++n) {
      float mx = -3.0e38f;
#pragma unroll
      for (int m = 0; m < 3; ++m)
#pragma unroll
        for (int r = 0; r < 4; ++r) {
          bool valid = (m < 2) || (quad * 4 + r < 10);  // key < 42
          mx = fmaxf(mx, valid ? st[m][n][r] : -3.0e38f);
        }
      mx = fmaxf(mx, __shfl_xor(mx, 16));
      mx = fmaxf(mx, __shfl_xor(mx, 32));
      float sm = 0.f, ev[3][4];
#pragma unroll
      for (int m = 0; m < 3; ++m)
#pragma unroll
        for (int r = 0; r < 4; ++r) {
          bool valid = (m < 2) || (quad * 4 + r < 10);
          float e = valid ? __expf(st[m][n][r] - mx) : 0.f;
          ev[m][r] = e; sm += e;
        }
      sm += __shfl_xor(sm, 16);
      sm += __shfl_xor(sm, 32);
      float inv = 1.f / sm;
#pragma unroll
      for (int m = 0; m < 3; ++m) {
        dwp[m][n][0] = pack2(ev[m][0] * inv, ev[m][1] * inv);
        dwp[m][n][1] = pack2(ev[m][2] * inv, ev[m][3] * inv);
      }
    }

    // === PV: both P and V^T fragments via shuffle-transpose (no LDS round-trip) ===
    f32x4 ov[3][2];
#pragma unroll
    for (int mtq = 0; mtq < 3; ++mtq) { ov[mtq][0] = f32x4{0,0,0,0}; ov[mtq][1] = f32x4{0,0,0,0}; }
    int sl0 = (2 * (quad & 1)) * 16 + c16, sl1 = sl0 + 16;
    bool hi = quad > 1;
#pragma unroll
    for (int ks = 0; ks < 2; ++ks) {
      // B-operand: V[g..g+7][d=nt*16+c16], g = koB(quad). dword m holds nodes (g+2m, g+2m+1):
      //   src lane = (((quad<<1)+(m>>1))&3)*16 + c16, reg = vp[nt][mt_src][m&1],
      //   mt_src = quad>>1 (ks=0) | 2 (ks=1).  Matches A-operand koB exactly (A=0 there).
      bf16x8 bv[2];
#pragma unroll
      for (int nt = 0; nt < 2; ++nt) {
        union { int i[4]; bf16x8 v; } U;
#pragma unroll
        for (int m = 0; m < 4; ++m) {
          int srcl = (((quad << 1) + (m >> 1)) & 3) * 16 + c16;
          if (ks == 0) {
            int x0 = __shfl(vp[nt][0][m & 1], srcl);
            int x1 = __shfl(vp[nt][1][m & 1], srcl);
            U.i[m] = (quad >> 1) ? x1 : x0;
          } else {
            U.i[m] = __shfl(vp[nt][2][m & 1], srcl);
          }
        }
        bv[nt] = U.v;
      }
      int lo = 2 * ks;
#pragma unroll
      for (int mtq = 0; mtq < 3; ++mtq) {
        int a0 = __shfl(dwp[lo][mtq][0], sl0), a1 = __shfl(dwp[lo][mtq][1], sl0);
        int a2 = __shfl(dwp[lo][mtq][0], sl1), a3 = __shfl(dwp[lo][mtq][1], sl1);
        int b0 = 0, b1 = 0, b2 = 0, b3 = 0;
        if (ks == 0) {
          b0 = __shfl(dwp[1][mtq][0], sl0); b1 = __shfl(dwp[1][mtq][1], sl0);
          b2 = __shfl(dwp[1][mtq][0], sl1); b3 = __shfl(dwp[1][mtq][1], sl1);
        }
        union { int i[4]; bf16x8 v; } A;
        A.i[0] = hi ? b0 : a0; A.i[1] = hi ? b1 : a1;
        A.i[2] = hi ? b2 : a2; A.i[3] = hi ? b3 : a3;
        ov[mtq][0] = MFMA(A.v, bv[0], ov[mtq][0]);
        ov[mtq][1] = MFMA(A.v, bv[1], ov[mtq][1]);
      }
    }
    // obf (= xbf alias) write: head slab cols w*32..w*32+31
#pragma unroll
    for (int mtq = 0; mtq < 3; ++mtq)
#pragma unroll
      for (int nt = 0; nt < 2; ++nt)
#pragma unroll
        for (int r = 0; r < 4; ++r) {
          int row = mtq * 16 + quad * 4 + r;
          xbf[row * 152 + w * 32 + nt * 16 + c16] = (__bf16)(row < NN_ ? ov[mtq][nt][r] : 0.f);
        }
    __syncthreads();

    // === attn-out + residual ===
    {
      const __bf16* aoW = wb + WB_AO + l * 128 * 128;
      const __bf16* Bs[2] = { aoW + ((2 * w) * 16 + c16) * 128, aoW + ((2 * w + 1) * 16 + c16) * 128 };
      f32x4 aa[2][3];
      gemm3xN<2, 4>(xbf, 152, Bs, c16, quad, aa);
#pragma unroll
      for (int nt = 0; nt < 2; ++nt) {
        float ab = ao_b[l * 128 + (2 * w + nt) * 16 + c16];
#pragma unroll
        for (int mt = 0; mt < 3; ++mt)
#pragma unroll
          for (int r = 0; r < 4; ++r) res[mt][nt][r] += aa[nt][mt][r] + ab;
      }
    }
    ln_update(res, ln1_g + l * 128, ln1_b + l * 128, xbf, part, statsA, statsB, tid, w, c16, quad);

    // === FF1 -> hbf (relu, bf16); two 2-tile passes (peak acc 24) ===
    {
      const __bf16* f1W = wb + WB_FF1 + l * 256 * 128;
#pragma unroll
      for (int pass = 0; pass < 2; ++pass) {
        const __bf16* Bs[2] = { f1W + ((4 * w + 2 * pass) * 16 + c16) * 128,
                                f1W + ((4 * w + 2 * pass + 1) * 16 + c16) * 128 };
        f32x4 fa[2][3];
        gemm3xN<2, 4>(xbf, 152, Bs, c16, quad, fa);
#pragma unroll
        for (int j = 0; j < 2; ++j) {
          int nt = 2 * pass + j;
          int col = (4 * w + nt) * 16 + c16;
          float b1 = ff1_b[l * 256 + col];
#pragma unroll
          for (int mt = 0; mt < 3; ++mt)
#pragma unroll
            for (int r = 0; r < 4; ++r) {
              int row = mt * 16 + quad * 4 + r;
              float v = fmaxf(fa[j][mt][r] + b1, 0.f);
              hbf[row * 280 + col] = (__bf16)(row < NN_ ? v : 0.f);
            }
        }
      }
    }
    __syncthreads();

    // === FF2 + residual ===
    {
      const __bf16* f2W = wb + WB_FF2 + l * 128 * 256;
      const __bf16* Bs[2] = { f2W + ((2 * w) * 16 + c16) * 256, f2W + ((2 * w + 1) * 16 + c16) * 256 };
      f32x4 fa[2][3];
      gemm3xN<2, 8>(hbf, 280, Bs, c16, quad, fa);
#pragma unroll
      for (int nt = 0; nt < 2; ++nt) {
        float fb2 = ff2_b[l * 128 + (2 * w + nt) * 16 + c16];
#pragma unroll
        for (int mt = 0; mt < 3; ++mt)
#pragma unroll
          for (int r = 0; r < 4; ++r) res[mt][nt][r] += fa[nt][mt][r] + fb2;
      }
    }
    ln_update(res, ln2_g + l * 128, ln2_b + l * 128, xbf, part, statsA, statsB, tid, w, c16, quad);
  }

  // ---- stage out: x_final (bf16) -> ws X[f][5376] ----
  {
    __bf16* Xf = Xg + (size_t)f * 5376;
    for (int c = tid; c < 672; c += 256) {
      int row = c >> 4, co = (c & 15) * 8;
      *(bf16x8*)(Xf + row * 128 + co) = ld8(xbf + row * 152 + co);
    }
  }
}

// ---------------- output projection + final LN, K split 4-way across waves ----------------
__global__ __launch_bounds__(1024) void wout_k(const __bf16* __restrict__ X,
                                               const __bf16* __restrict__ Wb,
                                               const float* __restrict__ b_out,
                                               const float* __restrict__ lnf_g,
                                               const float* __restrict__ lnf_b,
                                               float* __restrict__ out) {
  const int blk = blockIdx.x, tid = threadIdx.x;
  const int lane = tid & 63, w2 = tid >> 6, wc = w2 & 3, kh = w2 >> 2;  // wc 0..3, kh 0..3
  const int c16 = lane & 15, quad = lane >> 4;
  __shared__ float cout[64 * 132];
  f32x4 acc0{0,0,0,0}, acc1{0,0,0,0};
  const __bf16* Ar = X + (size_t)(blk * 16 + c16) * 5376 + kh * 1344;
  const __bf16* B0 = Wb + (size_t)((2 * wc) * 16 + c16) * 5376 + kh * 1344;
  const __bf16* B1 = Wb + (size_t)((2 * wc + 1) * 16 + c16) * 5376 + kh * 1344;
#pragma unroll 3
  for (int ks = 0; ks < 42; ++ks) {
    int ko = ks * 32 + quad * 8;
    bf16x8 a = ld8(Ar + ko);
    acc0 = MFMA(a, ld8(B0 + ko), acc0);
    acc1 = MFMA(a, ld8(B1 + ko), acc1);
  }
#pragma unroll
  for (int nt = 0; nt < 2; ++nt) {
    f32x4 a = nt ? acc1 : acc0;
#pragma unroll
    for (int r = 0; r < 4; ++r) cout[(kh * 16 + quad * 4 + r) * 132 + (2 * wc + nt) * 16 + c16] = a[r];
  }
  __syncthreads();
  if (w2 < 4) {
#pragma unroll
    for (int rr = 0; rr < 4; ++rr) {
      int row = w2 * 4 + rr;
      float v0 = cout[row * 132 + lane] + cout[(16 + row) * 132 + lane] +
                 cout[(32 + row) * 132 + lane] + cout[(48 + row) * 132 + lane] + b_out[lane];
      float v1 = cout[row * 132 + 64 + lane] + cout[(16 + row) * 132 + 64 + lane] +
                 cout[(32 + row) * 132 + 64 + lane] + cout[(48 + row) * 132 + 64 + lane] + b_out[64 + lane];
      float s = v0 + v1, ss = v0 * v0 + v1 * v1;
#pragma unroll
      for (int m = 1; m < 64; m <<= 1) { s += __shfl_xor(s, m); ss += __shfl_xor(ss, m); }
      float mu = s * 0.0078125f;
      float var = fmaxf(ss * 0.0078125f - mu * mu, 0.f);
      float rs = rsqrtf(var + 1e-5f);
      size_t o = (size_t)(blk * 16 + row) * 128;
      out[o + lane] = (v0 - mu) * rs * lnf_g[lane] + lnf_b[lane];
      out[o + 64 + lane] = (v1 - mu) * rs * lnf_g[64 + lane] + lnf_b[64 + lane];
    }
  }
}

extern "C" void kernel_launch(void* const* d_in, const int* in_sizes, int n_in,
                              void* d_out, int out_size, void* d_ws, size_t ws_size,
                              hipStream_t stream) {
  const float* forest     = (const float*)d_in[0];
  const int*   adjacency  = (const int*)d_in[1];
  const int*   node_order = (const int*)d_in[2];
  const float* W_in       = (const float*)d_in[3];
  const float* b_in       = (const float*)d_in[4];
  const float* qkv_w      = (const float*)d_in[5];
  const float* qkv_b      = (const float*)d_in[6];
  const float* ao_w       = (const float*)d_in[7];
  const float* ao_b       = (const float*)d_in[8];
  const float* ff1_w      = (const float*)d_in[9];
  const float* ff1_b      = (const float*)d_in[10];
  const float* ff2_w      = (const float*)d_in[11];
  const float* ff2_b      = (const float*)d_in[12];
  const float* ln1_g      = (const float*)d_in[13];
  const float* ln1_b      = (const float*)d_in[14];
  const float* ln2_g      = (const float*)d_in[15];
  const float* ln2_b      = (const float*)d_in[16];
  const float* b_out      = (const float*)d_in[18];
  const float* lnf_g      = (const float*)d_in[19];
  const float* lnf_b      = (const float*)d_in[20];
  __bf16* wb = (__bf16*)d_ws;
  float* out = (float*)d_out;

  prep_bf16<<<dim3(PREP_N / 256), dim3(256), 0, stream>>>(W_in, qkv_w, ao_w, ff1_w, ff2_w,
                                                          (const float*)d_in[17], wb);
  tree_enc<<<dim3(FB_), dim3(256), 0, stream>>>(forest, adjacency, node_order, b_in, qkv_b, ao_b,
                                                ff1_b, ff2_b, ln1_g, ln1_b, ln2_g, ln2_b, wb,
                                                wb + WB_X);
  wout_k<<<dim3(FB_ / 16), dim3(1024), 0, stream>>>(wb + WB_X, wb + WB_WOUT, b_out, lnf_g, lnf_b,
                                                    out);
}